// Round 8
// baseline (367.764 us; speedup 1.0000x reference)
//
#include <hip/hip_runtime.h>
#include <hip/hip_bf16.h>

typedef __attribute__((ext_vector_type(8))) short short8;
typedef __attribute__((ext_vector_type(4))) float floatx4;
typedef __attribute__((ext_vector_type(16))) float floatx16;
typedef unsigned short ushortt;

#define LOG2E 1.4426950408889634f
#define FLAG_MAGIC 0x5A17C0DEu

__device__ __forceinline__ float fast_exp2(float x) {
    return __builtin_amdgcn_exp2f(x);
}
__device__ __forceinline__ ushortt f2bf(float f) {
    unsigned int u = __float_as_uint(f);
    u += 0x7fffu + ((u >> 16) & 1u);
    return (ushortt)(u >> 16);
}
__device__ __forceinline__ unsigned int f2bf_pk(float a, float b) {
    float2 t; t.x = a; t.y = b;
    __hip_bfloat162 h = __float22bfloat162_rn(t);
    return *reinterpret_cast<unsigned int*>(&h);
}
__device__ __forceinline__ float bf2f(ushortt h) {
    return __uint_as_float(((unsigned int)h) << 16);
}

__device__ __forceinline__ float block_sum(float v, float* red) {
    #pragma unroll
    for (int off = 32; off > 0; off >>= 1) v += __shfl_down(v, off);
    int wid = threadIdx.x >> 6, ln = threadIdx.x & 63;
    __syncthreads();
    if (ln == 0) red[wid] = v;
    __syncthreads();
    return red[0] + red[1] + red[2] + red[3];
}

// --- inter-block handshake (co-resident grid; magic defeats poison; stale
// magic is benign: pipeline is deterministic -> bit-identical republish) ----
__device__ __forceinline__ void publish_flag(unsigned int* flag) {
    __syncthreads();                       // all waves' stores drained (vmcnt0 before barrier)
    if (threadIdx.x == 0) {
        __threadfence();                   // agent release: L2 writeback
        __hip_atomic_store(flag, FLAG_MAGIC, __ATOMIC_RELAXED, __HIP_MEMORY_SCOPE_AGENT);
    }
}
__device__ __forceinline__ void wait_flags(const unsigned int* flags, int n) {
    const int tid = threadIdx.x;
    for (;;) {
        unsigned int v = FLAG_MAGIC;
        if (tid < n)
            v = __hip_atomic_load(&flags[tid], __ATOMIC_RELAXED, __HIP_MEMORY_SCOPE_AGENT);
        if (__syncthreads_and(v == FLAG_MAGIC)) break;
        __builtin_amdgcn_s_sleep(4);
    }
    __threadfence();                       // agent acquire: L2 invalidate
}

// ===========================================================================
// FUSED PIPELINE: one dispatch. Blocks 0-7: sigma (0-3) / bf16-convert (4-7),
// then exit. Blocks 8..519 (wid=fid-8): qkv tile -> attn tile -> proj tile,
// each gated on flags. Weights are UNSCALED bf16; sigma applied in epilogues.
// 520 blocks <= 768 co-resident slots (launch_bounds(256,3), 33.8KB LDS).
// ===========================================================================
__global__ __launch_bounds__(256, 3) void fused_pipeline(
    const float* __restrict__ x,
    const float* __restrict__ Wf, const float* __restrict__ bfv,
    const float* __restrict__ Wg, const float* __restrict__ bgv,
    const float* __restrict__ Wh, const float* __restrict__ bhv,
    const float* __restrict__ Wv, const float* __restrict__ bvv,
    const float* __restrict__ uf, const float* __restrict__ ug,
    const float* __restrict__ uh, const float* __restrict__ uv,
    const float* __restrict__ gamma, float* __restrict__ out,
    float* __restrict__ sig, ushortt* __restrict__ wqkv, ushortt* __restrict__ wvb,
    ushortt* __restrict__ Qb, ushortt* __restrict__ Kb, ushortt* __restrict__ Vt,
    float2* __restrict__ ml, ushortt* __restrict__ Opart,
    unsigned int* __restrict__ fl_conv, unsigned int* __restrict__ fl_sig,
    unsigned int* __restrict__ fl_qkv, unsigned int* __restrict__ fl_attn) {
    __shared__ unsigned int smem[8448];
    const int fid = blockIdx.x;
    const int tid = threadIdx.x;

    // ---------------- pre-blocks: sigma / convert, then exit ---------------
    if (fid < 4) {                                    // sigma for matrix fid
        float* tv    = reinterpret_cast<float*>(smem);   // 512
        float* tvp   = tv + 512;                         // 256
        float* zpart = tvp + 256;                        // 256
        float* red   = zpart + 256;                      // 4
        const int mat = fid;
        if (mat < 3) {
            const float* W = (mat == 0) ? Wf : ((mat == 1) ? Wg : Wh);
            const float* u = (mat == 0) ? uf : ((mat == 1) ? ug : uh);
            {
                float s0 = 0.f, s1 = 0.f;
                #pragma unroll 8
                for (int r = 0; r < 64; ++r) {
                    float ur = u[r];
                    s0 += W[r * 512 + tid] * ur;
                    s1 += W[r * 512 + tid + 256] * ur;
                }
                tv[tid] = s0;
                tv[tid + 256] = s1;
            }
            __syncthreads();
            float p = tv[tid] * tv[tid] + tv[tid + 256] * tv[tid + 256];
            float nt2 = block_sum(p, red);
            float nt = fmaxf(sqrtf(nt2), 1e-12f);
            {
                int r = tid & 63, qq = tid >> 6;
                const float* Wr = W + r * 512 + qq * 128;
                const float* tq = tv + qq * 128;
                float part = 0.f;
                #pragma unroll 16
                for (int c = 0; c < 128; ++c) part += Wr[c] * tq[c];
                zpart[tid] = part;
            }
            __syncthreads();
            if (tid < 64) {
                float z = zpart[tid] + zpart[tid + 64] + zpart[tid + 128] + zpart[tid + 192];
                z = z * z;
                #pragma unroll
                for (int off = 32; off > 0; off >>= 1) z += __shfl_xor(z, off);
                if (tid == 0) sig[mat] = sqrtf(z) / nt;
            }
        } else {
            const float* W = Wv; const float* u = uv;
            {
                int c = tid & 63, rs = tid >> 6;
                float s0 = 0.f;
                #pragma unroll 8
                for (int r = rs * 128; r < rs * 128 + 128; ++r) s0 += W[r * 64 + c] * u[r];
                tvp[tid] = s0;
            }
            __syncthreads();
            if (tid < 64) tv[tid] = tvp[tid] + tvp[tid + 64] + tvp[tid + 128] + tvp[tid + 192];
            __syncthreads();
            float t = (tid < 64) ? tv[tid] : 0.f;
            float nt2 = block_sum(t * t, red);
            float nt = fmaxf(sqrtf(nt2), 1e-12f);
            {
                const float* w1 = W + (size_t)tid * 64;
                const float* w2 = W + (size_t)(tid + 256) * 64;
                float z1 = 0.f, z2 = 0.f;
                #pragma unroll 8
                for (int c = 0; c < 64; ++c) {
                    float tc = tv[c];
                    z1 += w1[c] * tc;
                    z2 += w2[c] * tc;
                }
                float zp = z1 * z1 + z2 * z2;
                float z2t = block_sum(zp, red);
                if (tid == 0) sig[3] = sqrtf(z2t) / nt;
            }
        }
        publish_flag(&fl_sig[mat]);
        return;
    }
    if (fid < 8) {                                    // unscaled bf16 convert
        const int mat = fid - 4;
        const float* W = (mat == 0) ? Wf : ((mat == 1) ? Wg : ((mat == 2) ? Wh : Wv));
        unsigned int* dst = (mat < 3)
            ? reinterpret_cast<unsigned int*>(wqkv + mat * 32768)
            : reinterpret_cast<unsigned int*>(wvb);
        const float4* W4 = reinterpret_cast<const float4*>(W);
        for (int i = tid; i < 8192; i += 256) {
            float4 wv4 = W4[i];
            dst[2 * i]     = f2bf_pk(wv4.x, wv4.y);
            dst[2 * i + 1] = f2bf_pk(wv4.z, wv4.w);
        }
        publish_flag(&fl_conv[mat]);
        return;
    }

    // ------------------------------ workers --------------------------------
    const int wid = fid - 8;                          // [0, 512)
    const int b = wid >> 7;

    // ========================= phase 1: qkv tile ==========================
    {
        const int n0 = (wid & 127) * 32;
        const int lane = tid & 63, w = tid >> 6;
        const int strip = w & 1, ksel = w >> 1;
        const int q = lane >> 4, l15 = lane & 15;
        const int sn = tid & 31, sg = tid >> 5;

        floatx4 acc[6];
        #pragma unroll
        for (int kt = 0; kt < 6; ++kt) acc[kt] = (floatx4){0.f, 0.f, 0.f, 0.f};

        const float* xb = x + ((size_t)b * 512) * 4096 + n0 + sn;
        const int sslot = sn * 32 + ((sg ^ (sn & 7)) << 2);
        float2 pre[4];
        #pragma unroll
        for (int i = 0; i < 4; ++i) {
            int c = sg * 8 + 2 * i;
            pre[i].x = xb[(size_t)c * 4096];
            pre[i].y = xb[(size_t)(c + 1) * 4096];
        }
        {
            uint4 pk;
            pk.x = f2bf_pk(pre[0].x, pre[0].y);
            pk.y = f2bf_pk(pre[1].x, pre[1].y);
            pk.z = f2bf_pk(pre[2].x, pre[2].y);
            pk.w = f2bf_pk(pre[3].x, pre[3].y);
            *reinterpret_cast<uint4*>(&smem[sslot]) = pk;
        }
        #pragma unroll
        for (int i = 0; i < 4; ++i) {
            int c = 64 + sg * 8 + 2 * i;
            pre[i].x = xb[(size_t)c * 4096];
            pre[i].y = xb[(size_t)(c + 1) * 4096];
        }

        wait_flags(fl_conv, 4);                       // weights ready (bf16)

        for (int it = 0; it < 8; ++it) {
            __syncthreads();
            if (it < 7) {
                uint4 pk;
                pk.x = f2bf_pk(pre[0].x, pre[0].y);
                pk.y = f2bf_pk(pre[1].x, pre[1].y);
                pk.z = f2bf_pk(pre[2].x, pre[2].y);
                pk.w = f2bf_pk(pre[3].x, pre[3].y);
                *reinterpret_cast<uint4*>(&smem[(((it + 1) & 1) << 10) + sslot]) = pk;
            }
            if (it < 6) {
                #pragma unroll
                for (int i = 0; i < 4; ++i) {
                    int c = (it + 2) * 64 + sg * 8 + 2 * i;
                    pre[i].x = xb[(size_t)c * 4096];
                    pre[i].y = xb[(size_t)(c + 1) * 4096];
                }
            }
            const int c0 = it * 64;
            const unsigned int* xr = &smem[((it & 1) << 10) + (16 * strip + l15) * 32];
            #pragma unroll
            for (int kc = 0; kc < 2; ++kc) {
                union { uint4 v; short8 s8; } af;
                af.v = *reinterpret_cast<const uint4*>(&xr[((4 * kc + q) ^ (l15 & 7)) << 2]);
                #pragma unroll
                for (int kt = 0; kt < 6; ++kt) {
                    short8 bb = *reinterpret_cast<const short8*>(
                        &wqkv[(size_t)(ksel * 96 + kt * 16 + l15) * 512 + c0 + kc * 32 + q * 8]);
                    acc[kt] = __builtin_amdgcn_mfma_f32_16x16x32_bf16(af.s8, bb, acc[kt], 0, 0, 0);
                }
            }
        }

        wait_flags(fl_sig, 4);                        // sigma ready
        float invf = 1.0f / sig[0];
        float invg = 1.0f / sig[1];
        float invh = 1.0f / sig[2];

        const int nloc = n0 + 16 * strip + 4 * q;
        if (ksel == 0) {
            #pragma unroll
            for (int kt = 0; kt < 4; ++kt) {          // Q (exp2-domain)
                int k = kt * 16 + l15;
                float bb = bfv[k];
                #pragma unroll
                for (int r = 0; r < 4; ++r)
                    Qb[((size_t)b * 4096 + nloc + r) * 64 + k] =
                        f2bf((acc[kt][r] * invf + bb) * LOG2E);
            }
            #pragma unroll
            for (int kt = 4; kt < 6; ++kt) {          // K rows 0..31
                int k = (kt - 4) * 16 + l15;
                float bb = bgv[k];
                #pragma unroll
                for (int r = 0; r < 4; ++r)
                    Kb[((size_t)b * 4096 + nloc + r) * 64 + k] = f2bf(acc[kt][r] * invg + bb);
            }
        } else {
            #pragma unroll
            for (int kt = 0; kt < 2; ++kt) {          // K rows 32..63
                int k = 32 + kt * 16 + l15;
                float bb = bgv[k];
                #pragma unroll
                for (int r = 0; r < 4; ++r)
                    Kb[((size_t)b * 4096 + nloc + r) * 64 + k] = f2bf(acc[kt][r] * invg + bb);
            }
        }
        __syncthreads();
        if (ksel == 1) {                              // V -> LDS (stride 17 dw)
            #pragma unroll
            for (int kt = 2; kt < 6; ++kt) {
                int d = (kt - 2) * 16 + l15;
                float bb = bhv[d];
                int base = d * 17 + 8 * strip + 2 * q;
                smem[base]     = f2bf_pk(acc[kt][0] * invh + bb, acc[kt][1] * invh + bb);
                smem[base + 1] = f2bf_pk(acc[kt][2] * invh + bb, acc[kt][3] * invh + bb);
            }
        }
        __syncthreads();
        {
            int d = tid >> 2, sgg = tid & 3;
            uint4 vv;
            vv.x = smem[d * 17 + sgg * 4 + 0]; vv.y = smem[d * 17 + sgg * 4 + 1];
            vv.z = smem[d * 17 + sgg * 4 + 2]; vv.w = smem[d * 17 + sgg * 4 + 3];
            *reinterpret_cast<uint4*>(&Vt[((size_t)b * 64 + d) * 4096 + n0 + sgg * 8]) = vv;
        }
        publish_flag(&fl_qkv[b * 128 + (wid & 127)]);
    }

    // ========================= phase 2: attn tile =========================
    {
        const int rem = wid & 127;
        const int s = rem & 1;
        const int n0 = (rem >> 1) * 64;
        const int KB = 32;

        wait_flags(&fl_qkv[b * 128], 128);            // batch's Q/K/V ready

        const int lane = tid & 63, w = tid >> 6;
        const int qh = w & 1, kh = w >> 1;
        const int l31 = lane & 31, h = lane >> 5;

        const ushortt* Kg = Kb + (size_t)b * 4096 * 64;
        const ushortt* Vg = Vt + (size_t)b * 64 * 4096;

        short8 bq[4];
        {
            const ushortt* Qg = Qb + ((size_t)b * 4096 + n0 + 32 * qh + l31) * 64;
            #pragma unroll
            for (int kc = 0; kc < 4; ++kc)
                bq[kc] = *reinterpret_cast<const short8*>(Qg + kc * 16 + 8 * h);
        }

        floatx16 ot0 = {}, ot1 = {};
        float l_i = 0.f;

        const int row = tid >> 2, seg = tid & 3;
        const int kbeg = s * KB, kend = kbeg + KB;
        const int rsw = row & 7;
        const int ws0 = row * 32 + ((((2 * seg)) ^ rsw) << 2);
        const int ws1 = row * 32 + ((((2 * seg + 1)) ^ rsw) << 2);

        uint4 ck0, ck1, cv0, cv1;
        {
            int nb = kbeg * 64;
            const ushortt* kp = Kg + (size_t)(nb + row) * 64 + seg * 16;
            ck0 = *reinterpret_cast<const uint4*>(kp);
            ck1 = *reinterpret_cast<const uint4*>(kp + 8);
            const ushortt* vp = Vg + (size_t)row * 4096 + nb + seg * 16;
            cv0 = *reinterpret_cast<const uint4*>(vp);
            cv1 = *reinterpret_cast<const uint4*>(vp + 8);
        }
        *reinterpret_cast<uint4*>(&smem[ws0]) = ck0;
        *reinterpret_cast<uint4*>(&smem[ws1]) = ck1;
        *reinterpret_cast<uint4*>(&smem[2048 + ws0]) = cv0;
        *reinterpret_cast<uint4*>(&smem[2048 + ws1]) = cv1;
        {
            int nb = (kbeg + 1) * 64;
            const ushortt* kp = Kg + (size_t)(nb + row) * 64 + seg * 16;
            ck0 = *reinterpret_cast<const uint4*>(kp);
            ck1 = *reinterpret_cast<const uint4*>(kp + 8);
            const ushortt* vp = Vg + (size_t)row * 4096 + nb + seg * 16;
            cv0 = *reinterpret_cast<const uint4*>(vp);
            cv1 = *reinterpret_cast<const uint4*>(vp + 8);
        }

        for (int kb = kbeg; kb < kend; ++kb) {
            const int cur = (kb - kbeg) & 1;
            const unsigned int rb = cur ? 4096u : 0u;
            const unsigned int wbs = cur ? 0u : 4096u;
            __syncthreads();
            if (kb + 1 < kend) {
                *reinterpret_cast<uint4*>(&smem[wbs + ws0]) = ck0;
                *reinterpret_cast<uint4*>(&smem[wbs + ws1]) = ck1;
                *reinterpret_cast<uint4*>(&smem[wbs + 2048 + ws0]) = cv0;
                *reinterpret_cast<uint4*>(&smem[wbs + 2048 + ws1]) = cv1;
            }
            if (kb + 2 < kend) {
                int nb = (kb + 2) * 64;
                const ushortt* kp = Kg + (size_t)(nb + row) * 64 + seg * 16;
                ck0 = *reinterpret_cast<const uint4*>(kp);
                ck1 = *reinterpret_cast<const uint4*>(kp + 8);
                const ushortt* vp = Vg + (size_t)row * 4096 + nb + seg * 16;
                cv0 = *reinterpret_cast<const uint4*>(vp);
                cv1 = *reinterpret_cast<const uint4*>(vp + 8);
            }

            floatx16 st = {};
            const unsigned int* kr = &smem[rb + (32 * kh + l31) * 32];
            const int esw = l31 & 7;
            __builtin_amdgcn_s_setprio(1);
            #pragma unroll
            for (int kc = 0; kc < 4; ++kc) {
                union { uint4 v; short8 s8; } af;
                af.v = *reinterpret_cast<const uint4*>(&kr[((2 * kc + h) ^ esw) << 2]);
                st = __builtin_amdgcn_mfma_f32_32x32x16_bf16(af.s8, bq[kc], st, 0, 0, 0);
            }
            __builtin_amdgcn_s_setprio(0);

            float p[16];
            float rs0 = 0.f, rs1 = 0.f, rs2 = 0.f, rs3 = 0.f;
            #pragma unroll
            for (int r = 0; r < 16; r += 4) {
                p[r]     = fast_exp2(st[r]);     rs0 += p[r];
                p[r + 1] = fast_exp2(st[r + 1]); rs1 += p[r + 1];
                p[r + 2] = fast_exp2(st[r + 2]); rs2 += p[r + 2];
                p[r + 3] = fast_exp2(st[r + 3]); rs3 += p[r + 3];
            }
            float rs = (rs0 + rs1) + (rs2 + rs3);
            rs += __shfl_xor(rs, 32);
            l_i += rs;

            unsigned int pk[8], sp[8];
            #pragma unroll
            for (int i = 0; i < 8; ++i) pk[i] = f2bf_pk(p[2 * i], p[2 * i + 1]);
            #pragma unroll
            for (int i = 0; i < 8; ++i) sp[i] = (unsigned int)__shfl_xor((int)pk[i], 32);
            union { unsigned int u[4]; short8 s8; } pb0, pb1;
            pb0.u[0] = h ? sp[2] : pk[0]; pb0.u[1] = h ? sp[3] : pk[1];
            pb0.u[2] = h ? pk[2] : sp[0]; pb0.u[3] = h ? pk[3] : sp[1];
            pb1.u[0] = h ? sp[6] : pk[4]; pb1.u[1] = h ? sp[7] : pk[5];
            pb1.u[2] = h ? pk[6] : sp[4]; pb1.u[3] = h ? pk[7] : sp[5];

            const unsigned int* vr0 = &smem[rb + 2048 + l31 * 32];
            const unsigned int* vr1 = &smem[rb + 2048 + (32 + l31) * 32];
            __builtin_amdgcn_s_setprio(1);
            #pragma unroll
            for (int c = 0; c < 2; ++c) {
                union { uint4 v; short8 s8; } af;
                af.v = *reinterpret_cast<const uint4*>(&vr0[((4 * kh + 2 * c + h) ^ esw) << 2]);
                ot0 = __builtin_amdgcn_mfma_f32_32x32x16_bf16(af.s8, c ? pb1.s8 : pb0.s8, ot0, 0, 0, 0);
                af.v = *reinterpret_cast<const uint4*>(&vr1[((4 * kh + 2 * c + h) ^ esw) << 2]);
                ot1 = __builtin_amdgcn_mfma_f32_32x32x16_bf16(af.s8, c ? pb1.s8 : pb0.s8, ot1, 0, 0, 0);
            }
            __builtin_amdgcn_s_setprio(0);
        }

        // merge kh halves (pure sums), write partial + l
        __syncthreads();
        if (h == 0) smem[8192 + w * 32 + l31] = __float_as_uint(l_i);
        __syncthreads();
        int pw = 2 * (1 - kh) + qh;
        float l2 = __uint_as_float(smem[8192 + pw * 32 + l31]);
        float lm = l_i + l2;
        if (kh == 0 && h == 0) {
            float2 v; v.x = 0.f; v.y = lm;
            ml[((size_t)s * 4 + b) * 4096 + n0 + 32 * qh + l31] = v;
        }
        float* om = reinterpret_cast<float*>(smem);
        if (kh == 0) {
            #pragma unroll
            for (int r = 0; r < 16; ++r) {
                int d0 = (r & 3) + 8 * (r >> 2) + 4 * h;
                om[(32 * qh + l31) * 65 + d0] = ot0[r];
                om[(32 * qh + l31) * 65 + 32 + d0] = ot1[r];
            }
        }
        __syncthreads();
        if (kh == 1) {
            #pragma unroll
            for (int r = 0; r < 16; ++r) {
                int d0 = (r & 3) + 8 * (r >> 2) + 4 * h;
                om[(32 * qh + l31) * 65 + d0] += ot0[r];
                om[(32 * qh + l31) * 65 + 32 + d0] += ot1[r];
            }
        }
        __syncthreads();
        {
            int qq = tid >> 2, dsg = tid & 3;
            unsigned int pkk[8];
            #pragma unroll
            for (int j = 0; j < 8; ++j)
                pkk[j] = f2bf_pk(om[qq * 65 + dsg * 16 + 2 * j], om[qq * 65 + dsg * 16 + 2 * j + 1]);
            ushortt* base = Opart + (((size_t)s * 4 + b) * 4096 + n0) * 64;
            uint4* d4 = reinterpret_cast<uint4*>(base + (size_t)qq * 64 + dsg * 16);
            uint4 o0; o0.x = pkk[0]; o0.y = pkk[1]; o0.z = pkk[2]; o0.w = pkk[3];
            uint4 o1; o1.x = pkk[4]; o1.y = pkk[5]; o1.z = pkk[6]; o1.w = pkk[7];
            d4[0] = o0; d4[1] = o1;
        }
        publish_flag(&fl_attn[b * 128 + rem]);
    }

    // ========================= phase 3: proj tile =========================
    {
        const int n0 = (wid & 127) * 32;
        const int pair = (wid & 127) >> 1;            // 64-px tile index

        wait_flags(&fl_attn[b * 128 + 2 * pair], 2);  // both s-halves ready

        ushortt* ol = reinterpret_cast<ushortt*>(smem);
        {   // combine S=2 partials (raw sums) into LDS
            int row = tid >> 3, t8 = tid & 7;
            int rg = n0 + row;
            float denom = ml[((size_t)b) * 4096 + rg].y
                        + ml[((size_t)4 + b) * 4096 + rg].y;
            float inv = 1.0f / denom;
            float acc8[8];
            #pragma unroll
            for (int j = 0; j < 8; ++j) acc8[j] = 0.f;
            #pragma unroll
            for (int s2 = 0; s2 < 2; ++s2) {
                union { uint4 v; ushortt hh[8]; } u;
                u.v = *reinterpret_cast<const uint4*>(
                    Opart + (((size_t)s2 * 4 + b) * 4096 + rg) * 64 + t8 * 8);
                #pragma unroll
                for (int j = 0; j < 8; ++j) acc8[j] += bf2f(u.hh[j]);
            }
            uint4 v;
            v.x = f2bf_pk(acc8[0] * inv, acc8[1] * inv);
            v.y = f2bf_pk(acc8[2] * inv, acc8[3] * inv);
            v.z = f2bf_pk(acc8[4] * inv, acc8[5] * inv);
            v.w = f2bf_pk(acc8[6] * inv, acc8[7] * inv);
            *reinterpret_cast<uint4*>(&ol[row * 72 + t8 * 8]) = v;
        }
        __syncthreads();

        const int w = tid >> 6, lane = tid & 63, q = lane >> 4, l15 = lane & 15;
        short8 bfr[2][2];
        #pragma unroll
        for (int u = 0; u < 2; ++u)
            #pragma unroll
            for (int kc = 0; kc < 2; ++kc)
                bfr[u][kc] = *reinterpret_cast<const short8*>(
                    &ol[(16 * u + l15) * 72 + 32 * kc + q * 8]);

        floatx4 acc[8][2];
        #pragma unroll
        for (int t = 0; t < 8; ++t)
            #pragma unroll
            for (int u = 0; u < 2; ++u) acc[t][u] = (floatx4){0.f, 0.f, 0.f, 0.f};

        const int cw = w * 128;
        #pragma unroll
        for (int t = 0; t < 8; ++t) {
            short8 a0 = *reinterpret_cast<const short8*>(
                &wvb[(size_t)(cw + 16 * t + l15) * 64 + q * 8]);
            short8 a1 = *reinterpret_cast<const short8*>(
                &wvb[(size_t)(cw + 16 * t + l15) * 64 + 32 + q * 8]);
            #pragma unroll
            for (int u = 0; u < 2; ++u) {
                acc[t][u] = __builtin_amdgcn_mfma_f32_16x16x32_bf16(a0, bfr[u][0], acc[t][u], 0, 0, 0);
                acc[t][u] = __builtin_amdgcn_mfma_f32_16x16x32_bf16(a1, bfr[u][1], acc[t][u], 0, 0, 0);
            }
        }

        float gm = gamma[0];
        float inv3 = 1.0f / sig[3];                   // wvb is unscaled
        #pragma unroll
        for (int t = 0; t < 8; ++t) {
            #pragma unroll
            for (int r = 0; r < 4; ++r) {
                int c = cw + 16 * t + 4 * q + r;
                float bb = bvv[c];
                #pragma unroll
                for (int u = 0; u < 2; ++u) {
                    int n = n0 + 16 * u + l15;
                    size_t idx = ((size_t)(b * 512 + c)) * 4096 + n;
                    out[idx] = gm * (acc[t][u][r] * inv3 + bb) + x[idx];
                }
            }
        }
    }
}

// ===========================================================================
// Fallback path (verified round-5/7 kernels, S=1) — used only if the
// workspace is too small for the fused pipeline's buffers+flags.
// ===========================================================================
__global__ __launch_bounds__(256) void sigma_kernel(
    const float* __restrict__ Wf, const float* __restrict__ uf,
    const float* __restrict__ Wg, const float* __restrict__ ug,
    const float* __restrict__ Wh, const float* __restrict__ uh,
    const float* __restrict__ Wv, const float* __restrict__ uv,
    float* __restrict__ sig,
    ushortt* __restrict__ wqkv, ushortt* __restrict__ wvb) {
    __shared__ float tv[512];
    __shared__ float tvp[256];
    __shared__ float zpart[256];
    __shared__ float red[4];
    __shared__ float ssig;
    const int mat = blockIdx.x, tid = threadIdx.x;

    if (mat < 3) {
        const float* W = (mat == 0) ? Wf : ((mat == 1) ? Wg : Wh);
        const float* u = (mat == 0) ? uf : ((mat == 1) ? ug : uh);
        {
            float s0 = 0.f, s1 = 0.f;
            #pragma unroll 8
            for (int r = 0; r < 64; ++r) {
                float ur = u[r];
                s0 += W[r * 512 + tid] * ur;
                s1 += W[r * 512 + tid + 256] * ur;
            }
            tv[tid] = s0;
            tv[tid + 256] = s1;
        }
        __syncthreads();
        float p = tv[tid] * tv[tid] + tv[tid + 256] * tv[tid + 256];
        float nt2 = block_sum(p, red);
        float nt = fmaxf(sqrtf(nt2), 1e-12f);
        {
            int r = tid & 63, qq = tid >> 6;
            const float* Wr = W + r * 512 + qq * 128;
            const float* tq = tv + qq * 128;
            float part = 0.f;
            #pragma unroll 16
            for (int c = 0; c < 128; ++c) part += Wr[c] * tq[c];
            zpart[tid] = part;
        }
        __syncthreads();
        if (tid < 64) {
            float z = zpart[tid] + zpart[tid + 64] + zpart[tid + 128] + zpart[tid + 192];
            z = z * z;
            #pragma unroll
            for (int off = 32; off > 0; off >>= 1) z += __shfl_xor(z, off);
            if (tid == 0) {
                float sg0 = sqrtf(z) / nt;
                sig[mat] = sg0;
                ssig = sg0;
            }
        }
        __syncthreads();
        float inv = 1.0f / ssig;
        const float4* W4 = reinterpret_cast<const float4*>(W);
        unsigned int* dst = reinterpret_cast<unsigned int*>(wqkv + mat * 32768);
        for (int i = tid; i < 8192; i += 256) {
            float4 wv = W4[i];
            dst[2 * i]     = f2bf_pk(wv.x * inv, wv.y * inv);
            dst[2 * i + 1] = f2bf_pk(wv.z * inv, wv.w * inv);
        }
    } else {
        const float* W = Wv; const float* u = uv;
        {
            int c = tid & 63, rs = tid >> 6;
            float s0 = 0.f;
            #pragma unroll 8
            for (int r = rs * 128; r < rs * 128 + 128; ++r) s0 += W[r * 64 + c] * u[r];
            tvp[tid] = s0;
        }
        __syncthreads();
        if (tid < 64) tv[tid] = tvp[tid] + tvp[tid + 64] + tvp[tid + 128] + tvp[tid + 192];
        __syncthreads();
        float t = (tid < 64) ? tv[tid] : 0.f;
        float nt2 = block_sum(t * t, red);
        float nt = fmaxf(sqrtf(nt2), 1e-12f);
        float sg3;
        {
            const float* w1 = W + (size_t)tid * 64;
            const float* w2 = W + (size_t)(tid + 256) * 64;
            float z1 = 0.f, z2 = 0.f;
            #pragma unroll 8
            for (int c = 0; c < 64; ++c) {
                float tc = tv[c];
                z1 += w1[c] * tc;
                z2 += w2[c] * tc;
            }
            float zp = z1 * z1 + z2 * z2;
            float z2t = block_sum(zp, red);
            sg3 = sqrtf(z2t) / nt;
            if (tid == 0) sig[3] = sg3;
        }
        float inv = 1.0f / sg3;
        const float4* W4 = reinterpret_cast<const float4*>(W);
        unsigned int* dst = reinterpret_cast<unsigned int*>(wvb);
        for (int i = tid; i < 8192; i += 256) {
            float4 wv = W4[i];
            dst[2 * i]     = f2bf_pk(wv.x * inv, wv.y * inv);
            dst[2 * i + 1] = f2bf_pk(wv.z * inv, wv.w * inv);
        }
    }
}

__global__ __launch_bounds__(256, 3) void qkv_kernel(
    const float* __restrict__ x, const ushortt* __restrict__ wqkv,
    const float* __restrict__ bfv, const float* __restrict__ bgv,
    const float* __restrict__ bhv,
    ushortt* __restrict__ Qb, ushortt* __restrict__ Kb, ushortt* __restrict__ Vt) {
    __shared__ unsigned int xs[2048];
    const int tid = threadIdx.x;
    const int n0 = blockIdx.x * 32, b = blockIdx.y;
    const int lane = tid & 63, w = tid >> 6;
    const int strip = w & 1, ksel = w >> 1;
    const int q = lane >> 4, l15 = lane & 15;
    const int sn = tid & 31, sg = tid >> 5;

    floatx4 acc[6];
    #pragma unroll
    for (int kt = 0; kt < 6; ++kt) acc[kt] = (floatx4){0.f, 0.f, 0.f, 0.f};

    const float* xb = x + ((size_t)b * 512) * 4096 + n0 + sn;
    const int sslot = sn * 32 + ((sg ^ (sn & 7)) << 2);
    float2 pre[4];
    #pragma unroll
    for (int i = 0; i < 4; ++i) {
        int c = sg * 8 + 2 * i;
        pre[i].x = xb[(size_t)c * 4096];
        pre[i].y = xb[(size_t)(c + 1) * 4096];
    }
    {
        uint4 pk;
        pk.x = f2bf_pk(pre[0].x, pre[0].y);
        pk.y = f2bf_pk(pre[1].x, pre[1].y);
        pk.z = f2bf_pk(pre[2].x, pre[2].y);
        pk.w = f2bf_pk(pre[3].x, pre[3].y);
        *reinterpret_cast<uint4*>(&xs[sslot]) = pk;
    }
    #pragma unroll
    for (int i = 0; i < 4; ++i) {
        int c = 64 + sg * 8 + 2 * i;
        pre[i].x = xb[(size_t)c * 4096];
        pre[i].y = xb[(size_t)(c + 1) * 4096];
    }

    for (int it = 0; it < 8; ++it) {
        __syncthreads();
        if (it < 7) {
            uint4 pk;
            pk.x = f2bf_pk(pre[0].x, pre[0].y);
            pk.y = f2bf_pk(pre[1].x, pre[1].y);
            pk.z = f2bf_pk(pre[2].x, pre[2].y);
            pk.w = f2bf_pk(pre[3].x, pre[3].y);
            *reinterpret_cast<uint4*>(&xs[(((it + 1) & 1) << 10) + sslot]) = pk;
        }
        if (it < 6) {
            #pragma unroll
            for (int i = 0; i < 4; ++i) {
                int c = (it + 2) * 64 + sg * 8 + 2 * i;
                pre[i].x = xb[(size_t)c * 4096];
                pre[i].y = xb[(size_t)(c + 1) * 4096];
            }
        }
        const int c0 = it * 64;
        const unsigned int* xr = &xs[((it & 1) << 10) + (16 * strip + l15) * 32];
        #pragma unroll
        for (int kc = 0; kc < 2; ++kc) {
            union { uint4 v; short8 s8; } af;
            af.v = *reinterpret_cast<const uint4*>(&xr[((4 * kc + q) ^ (l15 & 7)) << 2]);
            #pragma unroll
            for (int kt = 0; kt < 6; ++kt) {
                short8 bb = *reinterpret_cast<const short8*>(
                    &wqkv[(size_t)(ksel * 96 + kt * 16 + l15) * 512 + c0 + kc * 32 + q * 8]);
                acc[kt] = __builtin_amdgcn_mfma_f32_16x16x32_bf16(af.s8, bb, acc[kt], 0, 0, 0);
            }
        }
    }

    const int nloc = n0 + 16 * strip + 4 * q;
    if (ksel == 0) {
        #pragma unroll
        for (int kt = 0; kt < 4; ++kt) {
            int k = kt * 16 + l15;
            float bb = bfv[k];
            #pragma unroll
            for (int r = 0; r < 4; ++r)
                Qb[((size_t)b * 4096 + nloc + r) * 64 + k] = f2bf((acc[kt][r] + bb) * LOG2E);
        }
        #pragma unroll
        for (int kt = 4; kt < 6; ++kt) {
            int k = (kt - 4) * 16 + l15;
            float bb = bgv[k];
            #pragma unroll
            for (int r = 0; r < 4; ++r)
                Kb[((size_t)b * 4096 + nloc + r) * 64 + k] = f2bf(acc[kt][r] + bb);
        }
    } else {
        #pragma unroll
        for (int kt = 0; kt < 2; ++kt) {
            int k = 32 + kt * 16 + l15;
            float bb = bgv[k];
            #pragma unroll
            for (int r = 0; r < 4; ++r)
                Kb[((size_t)b * 4096 + nloc + r) * 64 + k] = f2bf(acc[kt][r] + bb);
        }
    }
    __syncthreads();
    if (ksel == 1) {
        #pragma unroll
        for (int kt = 2; kt < 6; ++kt) {
            int d = (kt - 2) * 16 + l15;
            float bb = bhv[d];
            int base = d * 17 + 8 * strip + 2 * q;
            xs[base]     = f2bf_pk(acc[kt][0] + bb, acc[kt][1] + bb);
            xs[base + 1] = f2bf_pk(acc[kt][2] + bb, acc[kt][3] + bb);
        }
    }
    __syncthreads();
    {
        int d = tid >> 2, sgg = tid & 3;
        uint4 vv;
        vv.x = xs[d * 17 + sgg * 4 + 0]; vv.y = xs[d * 17 + sgg * 4 + 1];
        vv.z = xs[d * 17 + sgg * 4 + 2]; vv.w = xs[d * 17 + sgg * 4 + 3];
        *reinterpret_cast<uint4*>(&Vt[((size_t)b * 64 + d) * 4096 + n0 + sgg * 8]) = vv;
    }
}

__global__ __launch_bounds__(256, 3) void attn_kernel(
    const ushortt* __restrict__ Qb, const ushortt* __restrict__ Kb,
    const ushortt* __restrict__ Vt, ushortt* __restrict__ Ob, int KB) {
    __shared__ unsigned int smem[8448];
    const int tid = threadIdx.x;
    const int n0 = blockIdx.x * 64, b = blockIdx.y;
    const int lane = tid & 63, w = tid >> 6;
    const int qh = w & 1, kh = w >> 1;
    const int l31 = lane & 31, h = lane >> 5;

    const ushortt* Kg = Kb + (size_t)b * 4096 * 64;
    const ushortt* Vg = Vt + (size_t)b * 64 * 4096;

    short8 bq[4];
    {
        const ushortt* Qg = Qb + ((size_t)b * 4096 + n0 + 32 * qh + l31) * 64;
        #pragma unroll
        for (int kc = 0; kc < 4; ++kc)
            bq[kc] = *reinterpret_cast<const short8*>(Qg + kc * 16 + 8 * h);
    }

    floatx16 ot0 = {}, ot1 = {};
    float l_i = 0.f;

    const int row = tid >> 2, seg = tid & 3;
    const int rsw = row & 7;
    const int ws0 = row * 32 + ((((2 * seg)) ^ rsw) << 2);
    const int ws1 = row * 32 + ((((2 * seg + 1)) ^ rsw) << 2);

    uint4 ck0, ck1, cv0, cv1;
    {
        const ushortt* kp = Kg + (size_t)row * 64 + seg * 16;
        ck0 = *reinterpret_cast<const uint4*>(kp);
        ck1 = *reinterpret_cast<const uint4*>(kp + 8);
        const ushortt* vp = Vg + (size_t)row * 4096 + seg * 16;
        cv0 = *reinterpret_cast<const uint4*>(vp);
        cv1 = *reinterpret_cast<const uint4*>(vp + 8);
    }
    *reinterpret_cast<uint4*>(&smem[ws0]) = ck0;
    *reinterpret_cast<uint4*>(&smem[ws1]) = ck1;
    *reinterpret_cast<uint4*>(&smem[2048 + ws0]) = cv0;
    *reinterpret_cast<uint4*>(&smem[2048 + ws1]) = cv1;
    {
        int nb = 64;
        const ushortt* kp = Kg + (size_t)(nb + row) * 64 + seg * 16;
        ck0 = *reinterpret_cast<const uint4*>(kp);
        ck1 = *reinterpret_cast<const uint4*>(kp + 8);
        const ushortt* vp = Vg + (size_t)row * 4096 + nb + seg * 16;
        cv0 = *reinterpret_cast<const uint4*>(vp);
        cv1 = *reinterpret_cast<const uint4*>(vp + 8);
    }

    for (int kb = 0; kb < KB; ++kb) {
        const int cur = kb & 1;
        const unsigned int rb = cur ? 4096u : 0u;
        const unsigned int wbs = cur ? 0u : 4096u;
        __syncthreads();
        if (kb + 1 < KB) {
            *reinterpret_cast<uint4*>(&smem[wbs + ws0]) = ck0;
            *reinterpret_cast<uint4*>(&smem[wbs + ws1]) = ck1;
            *reinterpret_cast<uint4*>(&smem[wbs + 2048 + ws0]) = cv0;
            *reinterpret_cast<uint4*>(&smem[wbs + 2048 + ws1]) = cv1;
        }
        if (kb + 2 < KB) {
            int nb = (kb + 2) * 64;
            const ushortt* kp = Kg + (size_t)(nb + row) * 64 + seg * 16;
            ck0 = *reinterpret_cast<const uint4*>(kp);
            ck1 = *reinterpret_cast<const uint4*>(kp + 8);
            const ushortt* vp = Vg + (size_t)row * 4096 + nb + seg * 16;
            cv0 = *reinterpret_cast<const uint4*>(vp);
            cv1 = *reinterpret_cast<const uint4*>(vp + 8);
        }

        floatx16 st = {};
        const unsigned int* kr = &smem[rb + (32 * kh + l31) * 32];
        const int esw = l31 & 7;
        #pragma unroll
        for (int kc = 0; kc < 4; ++kc) {
            union { uint4 v; short8 s8; } af;
            af.v = *reinterpret_cast<const uint4*>(&kr[((2 * kc + h) ^ esw) << 2]);
            st = __builtin_amdgcn_mfma_f32_32x32x16_bf16(af.s8, bq[kc], st, 0, 0, 0);
        }

        float p[16], rs = 0.f;
        #pragma unroll
        for (int r = 0; r < 16; ++r) { p[r] = fast_exp2(st[r]); rs += p[r]; }
        rs += __shfl_xor(rs, 32);
        l_i += rs;

        unsigned int pk[8], sp[8];
        #pragma unroll
        for (int i = 0; i < 8; ++i) pk[i] = f2bf_pk(p[2 * i], p[2 * i + 1]);
        #pragma unroll
        for (int i = 0; i < 8; ++i) sp[i] = (unsigned int)__shfl_xor((int)pk[i], 32);
        union { unsigned int u[4]; short8 s8; } pb0, pb1;
        pb0.u[0] = h ? sp[2] : pk[0]; pb0.u[1] = h ? sp[3] : pk[1];
        pb0.u[2] = h ? pk[2] : sp[0]; pb0.u[3] = h ? pk[3] : sp[1];
        pb1.u[0] = h ? sp[6] : pk[4]; pb1.u[1] = h ? sp[7] : pk[5];
        pb1.u[2] = h ? pk[6] : sp[4]; pb1.u[3] = h ? pk[7] : sp[5];

        const unsigned int* vr0 = &smem[rb + 2048 + l31 * 32];
        const unsigned int* vr1 = &smem[rb + 2048 + (32 + l31) * 32];
        #pragma unroll
        for (int c = 0; c < 2; ++c) {
            union { uint4 v; short8 s8; } af;
            af.v = *reinterpret_cast<const uint4*>(&vr0[((4 * kh + 2 * c + h) ^ esw) << 2]);
            ot0 = __builtin_amdgcn_mfma_f32_32x32x16_bf16(af.s8, c ? pb1.s8 : pb0.s8, ot0, 0, 0, 0);
            af.v = *reinterpret_cast<const uint4*>(&vr1[((4 * kh + 2 * c + h) ^ esw) << 2]);
            ot1 = __builtin_amdgcn_mfma_f32_32x32x16_bf16(af.s8, c ? pb1.s8 : pb0.s8, ot1, 0, 0, 0);
        }
    }

    __syncthreads();
    if (h == 0) smem[8192 + w * 32 + l31] = __float_as_uint(l_i);
    __syncthreads();
    int pw = 2 * (1 - kh) + qh;
    float l2 = __uint_as_float(smem[8192 + pw * 32 + l31]);
    float lm = l_i + l2;
    float sc = 1.0f / lm;
    float* om = reinterpret_cast<float*>(smem);
    if (kh == 0) {
        #pragma unroll
        for (int r = 0; r < 16; ++r) {
            int d0 = (r & 3) + 8 * (r >> 2) + 4 * h;
            om[(32 * qh + l31) * 65 + d0] = sc * ot0[r];
            om[(32 * qh + l31) * 65 + 32 + d0] = sc * ot1[r];
        }
    }
    __syncthreads();
    if (kh == 1) {
        #pragma unroll
        for (int r = 0; r < 16; ++r) {
            int d0 = (r & 3) + 8 * (r >> 2) + 4 * h;
            om[(32 * qh + l31) * 65 + d0] += sc * ot0[r];
            om[(32 * qh + l31) * 65 + 32 + d0] += sc * ot1[r];
        }
    }
    __syncthreads();
    {
        int qq = tid >> 2, dsg = tid & 3;
        unsigned int pkk[8];
        #pragma unroll
        for (int j = 0; j < 8; ++j)
            pkk[j] = f2bf_pk(om[qq * 65 + dsg * 16 + 2 * j], om[qq * 65 + dsg * 16 + 2 * j + 1]);
        ushortt* base = Ob + ((size_t)b * 4096 + n0) * 64;
        uint4* d4 = reinterpret_cast<uint4*>(base + (size_t)qq * 64 + dsg * 16);
        uint4 o0; o0.x = pkk[0]; o0.y = pkk[1]; o0.z = pkk[2]; o0.w = pkk[3];
        uint4 o1; o1.x = pkk[4]; o1.y = pkk[5]; o1.z = pkk[6]; o1.w = pkk[7];
        d4[0] = o0; d4[1] = o1;
    }
}

__global__ __launch_bounds__(256, 3) void proj_kernel(
    const ushortt* __restrict__ Ob, const ushortt* __restrict__ wvb,
    const float* __restrict__ bv, const float* __restrict__ gamma,
    const float* __restrict__ x, float* __restrict__ out) {
    __shared__ ushortt ol[32 * 72];
    const int tid = threadIdx.x;
    const int n0 = blockIdx.x * 32, b = blockIdx.y;

    {
        int row = tid >> 3, t8 = tid & 7;
        uint4 v = *reinterpret_cast<const uint4*>(
            Ob + ((size_t)b * 4096 + n0 + row) * 64 + t8 * 8);
        *reinterpret_cast<uint4*>(&ol[row * 72 + t8 * 8]) = v;
    }
    __syncthreads();

    const int w = tid >> 6, lane = tid & 63, q = lane >> 4, l15 = lane & 15;
    short8 bfr[2][2];
    #pragma unroll
    for (int u = 0; u < 2; ++u)
        #pragma unroll
        for (int kc = 0; kc < 2; ++kc)
            bfr[u][kc] = *reinterpret_cast<const short8*>(
                &ol[(16 * u + l15) * 72 + 32 * kc + q * 8]);

    floatx4 acc[8][2];
    #pragma unroll
    for (int t = 0; t < 8; ++t)
        #pragma unroll
        for (int u = 0; u < 2; ++u) acc[t][u] = (floatx4){0.f, 0.f, 0.f, 0.f};

    const int cw = w * 128;
    #pragma unroll
    for (int t = 0; t < 8; ++t) {
        short8 a0 = *reinterpret_cast<const short8*>(
            &wvb[(size_t)(cw + 16 * t + l15) * 64 + q * 8]);
        short8 a1 = *reinterpret_cast<const short8*>(
            &wvb[(size_t)(cw + 16 * t + l15) * 64 + 32 + q * 8]);
        #pragma unroll
        for (int u = 0; u < 2; ++u) {
            acc[t][u] = __builtin_amdgcn_mfma_f32_16x16x32_bf16(a0, bfr[u][0], acc[t][u], 0, 0, 0);
            acc[t][u] = __builtin_amdgcn_mfma_f32_16x16x32_bf16(a1, bfr[u][1], acc[t][u], 0, 0, 0);
        }
    }

    float gm = gamma[0];
    #pragma unroll
    for (int t = 0; t < 8; ++t) {
        #pragma unroll
        for (int r = 0; r < 4; ++r) {
            int c = cw + 16 * t + 4 * q + r;
            float bb = bv[c];
            #pragma unroll
            for (int u = 0; u < 2; ++u) {
                int n = n0 + 16 * u + l15;
                size_t idx = ((size_t)(b * 512 + c)) * 4096 + n;
                out[idx] = gm * (acc[t][u][r] + bb) + x[idx];
            }
        }
    }
}

// ---------------------------------------------------------------------------
extern "C" void kernel_launch(void* const* d_in, const int* in_sizes, int n_in,
                              void* d_out, int out_size, void* d_ws, size_t ws_size,
                              hipStream_t stream) {
    const float* x   = (const float*)d_in[0];
    const float* Wf  = (const float*)d_in[1];
    const float* bf_ = (const float*)d_in[2];
    const float* Wg  = (const float*)d_in[3];
    const float* bg_ = (const float*)d_in[4];
    const float* Wh  = (const float*)d_in[5];
    const float* bh_ = (const float*)d_in[6];
    const float* Wv  = (const float*)d_in[7];
    const float* bv_ = (const float*)d_in[8];
    const float* uf  = (const float*)d_in[9];
    const float* ug  = (const float*)d_in[10];
    const float* uh  = (const float*)d_in[11];
    const float* uv  = (const float*)d_in[12];
    const float* gm  = (const float*)d_in[13];
    float* out = (float*)d_out;

    char* ws = (char*)d_ws;
    float*   sig   = (float*)ws;                         // 256 B
    ushortt* wqkv  = (ushortt*)(ws + 256);               // 196608
    ushortt* wvb   = (ushortt*)(ws + 196864);            // 65536
    ushortt* Qb    = (ushortt*)(ws + 262400);            // 2 MB
    ushortt* Kb    = (ushortt*)(ws + 2359552);           // 2 MB
    ushortt* Vt    = (ushortt*)(ws + 4456704);           // 2 MB  [b][d][n]
    ushortt* Ob    = (ushortt*)(ws + 6553856);           // 2 MB (fallback)
    float2*  ml    = (float2*)(ws + 8651008);            // 512 KB
    ushortt* Opart = (ushortt*)(ws + 9175296);           // 4 MB bf16 (S=2)
    unsigned int* fl_conv = (unsigned int*)(ws + 13369600);  // 4 dw
    unsigned int* fl_sig  = fl_conv + 4;                     // 4 dw
    unsigned int* fl_qkv  = fl_sig + 4;                      // 512 dw
    unsigned int* fl_attn = fl_qkv + 512;                    // 512 dw

    if (ws_size >= (size_t)13400000) {
        fused_pipeline<<<520, 256, 0, stream>>>(
            x, Wf, bf_, Wg, bg_, Wh, bh_, Wv, bv_, uf, ug, uh, uv, gm, out,
            sig, wqkv, wvb, Qb, Kb, Vt, ml, Opart,
            fl_conv, fl_sig, fl_qkv, fl_attn);
    } else {
        sigma_kernel<<<4, 256, 0, stream>>>(Wf, uf, Wg, ug, Wh, uh, Wv, uv, sig, wqkv, wvb);
        qkv_kernel<<<dim3(128, 4), 256, 0, stream>>>(x, wqkv, bf_, bg_, bh_, Qb, Kb, Vt);
        attn_kernel<<<dim3(64, 4), 256, 0, stream>>>(Qb, Kb, Vt, Ob, 64);
        proj_kernel<<<dim3(128, 4), 256, 0, stream>>>(Ob, wvb, bv_, gm, x, out);
    }
}

// Round 9
// 246.293 us; speedup vs baseline: 1.4932x; 1.4932x over previous
//
#include <hip/hip_runtime.h>
#include <hip/hip_bf16.h>

typedef __attribute__((ext_vector_type(8))) short short8;
typedef __attribute__((ext_vector_type(4))) float floatx4;
typedef __attribute__((ext_vector_type(16))) float floatx16;
typedef unsigned short ushortt;

#define LOG2E 1.4426950408889634f
#define FLAG_MAGIC 0x5A17C0DEu

__device__ __forceinline__ float fast_exp2(float x) {
    return __builtin_amdgcn_exp2f(x);
}
__device__ __forceinline__ ushortt f2bf(float f) {
    unsigned int u = __float_as_uint(f);
    u += 0x7fffu + ((u >> 16) & 1u);
    return (ushortt)(u >> 16);
}
__device__ __forceinline__ unsigned int f2bf_pk(float a, float b) {
    float2 t; t.x = a; t.y = b;
    __hip_bfloat162 h = __float22bfloat162_rn(t);
    return *reinterpret_cast<unsigned int*>(&h);
}
__device__ __forceinline__ float bf2f(ushortt h) {
    return __uint_as_float(((unsigned int)h) << 16);
}

__device__ __forceinline__ float block_sum(float v, float* red) {
    #pragma unroll
    for (int off = 32; off > 0; off >>= 1) v += __shfl_down(v, off);
    int wid = threadIdx.x >> 6, ln = threadIdx.x & 63;
    __syncthreads();
    if (ln == 0) red[wid] = v;
    __syncthreads();
    return red[0] + red[1] + red[2] + red[3];
}

// --- tiny-producer handshake (R8-validated pattern; only 8 flags total) ----
__device__ __forceinline__ void publish_flag(unsigned int* flag) {
    __syncthreads();
    if (threadIdx.x == 0) {
        __threadfence();                   // release: L2 writeback
        __hip_atomic_store(flag, FLAG_MAGIC, __ATOMIC_RELAXED, __HIP_MEMORY_SCOPE_AGENT);
    }
}
__device__ __forceinline__ void wait_flags(const unsigned int* flags, int n) {
    const int tid = threadIdx.x;
    for (;;) {
        unsigned int v = FLAG_MAGIC;
        if (tid < n)
            v = __hip_atomic_load(&flags[tid], __ATOMIC_RELAXED, __HIP_MEMORY_SCOPE_AGENT);
        if (__syncthreads_and(v == FLAG_MAGIC)) break;
        __builtin_amdgcn_s_sleep(4);
    }
    __threadfence();                       // acquire: L2 invalidate
}

// ===========================================================================
// sigma + weight-convert + qkv in ONE dispatch (520 blocks).
// Blocks 0-3: sigma for matrix fid -> fl_sig. Blocks 4-7: UNSCALED bf16
// convert -> fl_conv. Blocks 8-519: R7 qkv tile; wait fl_conv before the
// MFMA loop (producers ~5us vs worker prologue ~5us -> near-zero spin);
// wait fl_sig only at the epilogue; apply 1/sigma there (R8-validated).
// All 520 blocks co-resident (<=768 slots at 8KB LDS / lb(256,3)).
// ===========================================================================
__global__ __launch_bounds__(256, 3) void qkv_fused_kernel(
    const float* __restrict__ x,
    const float* __restrict__ Wf, const float* __restrict__ bfv,
    const float* __restrict__ Wg, const float* __restrict__ bgv,
    const float* __restrict__ Wh, const float* __restrict__ bhv,
    const float* __restrict__ Wv,
    const float* __restrict__ uf, const float* __restrict__ ug,
    const float* __restrict__ uh, const float* __restrict__ uv,
    float* __restrict__ sig,
    ushortt* __restrict__ wqkv, ushortt* __restrict__ wvb,
    ushortt* __restrict__ Qb, ushortt* __restrict__ Kb, ushortt* __restrict__ Vt,
    unsigned int* __restrict__ fl_conv, unsigned int* __restrict__ fl_sig) {
    __shared__ unsigned int smem[2048];
    const int fid = blockIdx.x;
    const int tid = threadIdx.x;

    if (fid < 4) {                         // ---- sigma for matrix fid ----
        float* tv    = reinterpret_cast<float*>(smem);   // 512
        float* tvp   = tv + 512;                         // 256
        float* zpart = tvp + 256;                        // 256
        float* red   = zpart + 256;                      // 4
        const int mat = fid;
        if (mat < 3) {
            const float* W = (mat == 0) ? Wf : ((mat == 1) ? Wg : Wh);
            const float* u = (mat == 0) ? uf : ((mat == 1) ? ug : uh);
            {
                float s0 = 0.f, s1 = 0.f;
                #pragma unroll 8
                for (int r = 0; r < 64; ++r) {
                    float ur = u[r];
                    s0 += W[r * 512 + tid] * ur;
                    s1 += W[r * 512 + tid + 256] * ur;
                }
                tv[tid] = s0;
                tv[tid + 256] = s1;
            }
            __syncthreads();
            float p = tv[tid] * tv[tid] + tv[tid + 256] * tv[tid + 256];
            float nt2 = block_sum(p, red);
            float nt = fmaxf(sqrtf(nt2), 1e-12f);
            {
                int r = tid & 63, qq = tid >> 6;
                const float* Wr = W + r * 512 + qq * 128;
                const float* tq = tv + qq * 128;
                float part = 0.f;
                #pragma unroll 16
                for (int c = 0; c < 128; ++c) part += Wr[c] * tq[c];
                zpart[tid] = part;
            }
            __syncthreads();
            if (tid < 64) {
                float z = zpart[tid] + zpart[tid + 64] + zpart[tid + 128] + zpart[tid + 192];
                z = z * z;
                #pragma unroll
                for (int off = 32; off > 0; off >>= 1) z += __shfl_xor(z, off);
                if (tid == 0) sig[mat] = sqrtf(z) / nt;
            }
        } else {
            const float* W = Wv; const float* u = uv;
            {
                int c = tid & 63, rs = tid >> 6;
                float s0 = 0.f;
                #pragma unroll 8
                for (int r = rs * 128; r < rs * 128 + 128; ++r) s0 += W[r * 64 + c] * u[r];
                tvp[tid] = s0;
            }
            __syncthreads();
            if (tid < 64) tv[tid] = tvp[tid] + tvp[tid + 64] + tvp[tid + 128] + tvp[tid + 192];
            __syncthreads();
            float t = (tid < 64) ? tv[tid] : 0.f;
            float nt2 = block_sum(t * t, red);
            float nt = fmaxf(sqrtf(nt2), 1e-12f);
            {
                const float* w1 = W + (size_t)tid * 64;
                const float* w2 = W + (size_t)(tid + 256) * 64;
                float z1 = 0.f, z2 = 0.f;
                #pragma unroll 8
                for (int c = 0; c < 64; ++c) {
                    float tc = tv[c];
                    z1 += w1[c] * tc;
                    z2 += w2[c] * tc;
                }
                float zp = z1 * z1 + z2 * z2;
                float z2t = block_sum(zp, red);
                if (tid == 0) sig[3] = sqrtf(z2t) / nt;
            }
        }
        publish_flag(&fl_sig[mat]);
        return;
    }
    if (fid < 8) {                         // ---- unscaled bf16 convert ----
        const int mat = fid - 4;
        const float* W = (mat == 0) ? Wf : ((mat == 1) ? Wg : ((mat == 2) ? Wh : Wv));
        unsigned int* dst = (mat < 3)
            ? reinterpret_cast<unsigned int*>(wqkv + mat * 32768)
            : reinterpret_cast<unsigned int*>(wvb);
        const float4* W4 = reinterpret_cast<const float4*>(W);
        for (int i = tid; i < 8192; i += 256) {
            float4 wv4 = W4[i];
            dst[2 * i]     = f2bf_pk(wv4.x, wv4.y);
            dst[2 * i + 1] = f2bf_pk(wv4.z, wv4.w);
        }
        publish_flag(&fl_conv[mat]);
        return;
    }

    // ---------------------------- qkv worker -------------------------------
    const int wid = fid - 8;
    const int n0 = (wid & 127) * 32, b = wid >> 7;
    const int lane = tid & 63, w = tid >> 6;
    const int strip = w & 1, ksel = w >> 1;
    const int q = lane >> 4, l15 = lane & 15;
    const int sn = tid & 31, sg = tid >> 5;

    floatx4 acc[6];
    #pragma unroll
    for (int kt = 0; kt < 6; ++kt) acc[kt] = (floatx4){0.f, 0.f, 0.f, 0.f};

    const float* xb = x + ((size_t)b * 512) * 4096 + n0 + sn;
    const int sslot = sn * 32 + ((sg ^ (sn & 7)) << 2);
    float2 pre[4];
    #pragma unroll
    for (int i = 0; i < 4; ++i) {
        int c = sg * 8 + 2 * i;
        pre[i].x = xb[(size_t)c * 4096];
        pre[i].y = xb[(size_t)(c + 1) * 4096];
    }
    {
        uint4 pk;
        pk.x = f2bf_pk(pre[0].x, pre[0].y);
        pk.y = f2bf_pk(pre[1].x, pre[1].y);
        pk.z = f2bf_pk(pre[2].x, pre[2].y);
        pk.w = f2bf_pk(pre[3].x, pre[3].y);
        *reinterpret_cast<uint4*>(&smem[sslot]) = pk;
    }
    #pragma unroll
    for (int i = 0; i < 4; ++i) {
        int c = 64 + sg * 8 + 2 * i;
        pre[i].x = xb[(size_t)c * 4096];
        pre[i].y = xb[(size_t)(c + 1) * 4096];
    }

    wait_flags(fl_conv, 4);                // bf16 weights ready (short spin)

    for (int it = 0; it < 8; ++it) {
        __syncthreads();
        if (it < 7) {
            uint4 pk;
            pk.x = f2bf_pk(pre[0].x, pre[0].y);
            pk.y = f2bf_pk(pre[1].x, pre[1].y);
            pk.z = f2bf_pk(pre[2].x, pre[2].y);
            pk.w = f2bf_pk(pre[3].x, pre[3].y);
            *reinterpret_cast<uint4*>(&smem[(((it + 1) & 1) << 10) + sslot]) = pk;
        }
        if (it < 6) {
            #pragma unroll
            for (int i = 0; i < 4; ++i) {
                int c = (it + 2) * 64 + sg * 8 + 2 * i;
                pre[i].x = xb[(size_t)c * 4096];
                pre[i].y = xb[(size_t)(c + 1) * 4096];
            }
        }
        const int c0 = it * 64;
        const unsigned int* xr = &smem[((it & 1) << 10) + (16 * strip + l15) * 32];
        #pragma unroll
        for (int kc = 0; kc < 2; ++kc) {
            union { uint4 v; short8 s8; } af;
            af.v = *reinterpret_cast<const uint4*>(&xr[((4 * kc + q) ^ (l15 & 7)) << 2]);
            #pragma unroll
            for (int kt = 0; kt < 6; ++kt) {
                short8 bb = *reinterpret_cast<const short8*>(
                    &wqkv[(size_t)(ksel * 96 + kt * 16 + l15) * 512 + c0 + kc * 32 + q * 8]);
                acc[kt] = __builtin_amdgcn_mfma_f32_16x16x32_bf16(af.s8, bb, acc[kt], 0, 0, 0);
            }
        }
    }

    wait_flags(fl_sig, 4);                 // sigma ready (zero spin by now)
    float invf = 1.0f / sig[0];
    float invg = 1.0f / sig[1];
    float invh = 1.0f / sig[2];

    const int nloc = n0 + 16 * strip + 4 * q;
    if (ksel == 0) {
        #pragma unroll
        for (int kt = 0; kt < 4; ++kt) {   // Q (exp2-domain)
            int k = kt * 16 + l15;
            float bb = bfv[k];
            #pragma unroll
            for (int r = 0; r < 4; ++r)
                Qb[((size_t)b * 4096 + nloc + r) * 64 + k] =
                    f2bf((acc[kt][r] * invf + bb) * LOG2E);
        }
        #pragma unroll
        for (int kt = 4; kt < 6; ++kt) {   // K rows 0..31
            int k = (kt - 4) * 16 + l15;
            float bb = bgv[k];
            #pragma unroll
            for (int r = 0; r < 4; ++r)
                Kb[((size_t)b * 4096 + nloc + r) * 64 + k] = f2bf(acc[kt][r] * invg + bb);
        }
    } else {
        #pragma unroll
        for (int kt = 0; kt < 2; ++kt) {   // K rows 32..63
            int k = 32 + kt * 16 + l15;
            float bb = bgv[k];
            #pragma unroll
            for (int r = 0; r < 4; ++r)
                Kb[((size_t)b * 4096 + nloc + r) * 64 + k] = f2bf(acc[kt][r] * invg + bb);
        }
    }
    __syncthreads();
    if (ksel == 1) {                       // V -> LDS [d][n/2] (stride 17 dw)
        #pragma unroll
        for (int kt = 2; kt < 6; ++kt) {
            int d = (kt - 2) * 16 + l15;
            float bb = bhv[d];
            int base = d * 17 + 8 * strip + 2 * q;
            smem[base]     = f2bf_pk(acc[kt][0] * invh + bb, acc[kt][1] * invh + bb);
            smem[base + 1] = f2bf_pk(acc[kt][2] * invh + bb, acc[kt][3] * invh + bb);
        }
    }
    __syncthreads();
    {
        int d = tid >> 2, sgg = tid & 3;
        uint4 vv;
        vv.x = smem[d * 17 + sgg * 4 + 0]; vv.y = smem[d * 17 + sgg * 4 + 1];
        vv.z = smem[d * 17 + sgg * 4 + 2]; vv.w = smem[d * 17 + sgg * 4 + 3];
        *reinterpret_cast<uint4*>(&Vt[((size_t)b * 64 + d) * 4096 + n0 + sgg * 8]) = vv;
    }
}

// ---------------------------------------------------------------------------
// Flash attention, no-max softmax (R7, verified): p = exp2(st) directly,
// partials are raw (O, l) sums. S=2 (KB=32). 32x32x16 MFMA, XOR-swizzled
// b128 LDS, dbuf K/V, one barrier per KV-step, setprio around MFMA.
// ---------------------------------------------------------------------------
__global__ __launch_bounds__(256, 3) void attn_kernel(
    const ushortt* __restrict__ Qb, const ushortt* __restrict__ Kb,
    const ushortt* __restrict__ Vt, ushortt* __restrict__ Opart,
    float2* __restrict__ ml, ushortt* __restrict__ Ob, int KB) {
    __shared__ unsigned int smem[8448];
    const int tid = threadIdx.x;
    const int n0 = blockIdx.x * 64, b = blockIdx.y, s = blockIdx.z;
    const int lane = tid & 63, w = tid >> 6;
    const int qh = w & 1, kh = w >> 1;
    const int l31 = lane & 31, h = lane >> 5;

    const ushortt* Kg = Kb + (size_t)b * 4096 * 64;
    const ushortt* Vg = Vt + (size_t)b * 64 * 4096;

    short8 bq[4];
    {
        const ushortt* Qg = Qb + ((size_t)b * 4096 + n0 + 32 * qh + l31) * 64;
        #pragma unroll
        for (int kc = 0; kc < 4; ++kc)
            bq[kc] = *reinterpret_cast<const short8*>(Qg + kc * 16 + 8 * h);
    }

    floatx16 ot0 = {}, ot1 = {};
    float l_i = 0.f;

    const int row = tid >> 2, seg = tid & 3;
    const int kbeg = s * KB, kend = kbeg + KB;
    const int rsw = row & 7;
    const int ws0 = row * 32 + ((((2 * seg)) ^ rsw) << 2);
    const int ws1 = row * 32 + ((((2 * seg + 1)) ^ rsw) << 2);

    uint4 ck0, ck1, cv0, cv1;
    {
        int nb = kbeg * 64;
        const ushortt* kp = Kg + (size_t)(nb + row) * 64 + seg * 16;
        ck0 = *reinterpret_cast<const uint4*>(kp);
        ck1 = *reinterpret_cast<const uint4*>(kp + 8);
        const ushortt* vp = Vg + (size_t)row * 4096 + nb + seg * 16;
        cv0 = *reinterpret_cast<const uint4*>(vp);
        cv1 = *reinterpret_cast<const uint4*>(vp + 8);
    }
    *reinterpret_cast<uint4*>(&smem[ws0]) = ck0;
    *reinterpret_cast<uint4*>(&smem[ws1]) = ck1;
    *reinterpret_cast<uint4*>(&smem[2048 + ws0]) = cv0;
    *reinterpret_cast<uint4*>(&smem[2048 + ws1]) = cv1;
    if (kbeg + 1 < kend) {
        int nb = (kbeg + 1) * 64;
        const ushortt* kp = Kg + (size_t)(nb + row) * 64 + seg * 16;
        ck0 = *reinterpret_cast<const uint4*>(kp);
        ck1 = *reinterpret_cast<const uint4*>(kp + 8);
        const ushortt* vp = Vg + (size_t)row * 4096 + nb + seg * 16;
        cv0 = *reinterpret_cast<const uint4*>(vp);
        cv1 = *reinterpret_cast<const uint4*>(vp + 8);
    }

    for (int kb = kbeg; kb < kend; ++kb) {
        const int cur = (kb - kbeg) & 1;
        const unsigned int rb = cur ? 4096u : 0u;
        const unsigned int wbs = cur ? 0u : 4096u;
        __syncthreads();
        if (kb + 1 < kend) {
            *reinterpret_cast<uint4*>(&smem[wbs + ws0]) = ck0;
            *reinterpret_cast<uint4*>(&smem[wbs + ws1]) = ck1;
            *reinterpret_cast<uint4*>(&smem[wbs + 2048 + ws0]) = cv0;
            *reinterpret_cast<uint4*>(&smem[wbs + 2048 + ws1]) = cv1;
        }
        if (kb + 2 < kend) {
            int nb = (kb + 2) * 64;
            const ushortt* kp = Kg + (size_t)(nb + row) * 64 + seg * 16;
            ck0 = *reinterpret_cast<const uint4*>(kp);
            ck1 = *reinterpret_cast<const uint4*>(kp + 8);
            const ushortt* vp = Vg + (size_t)row * 4096 + nb + seg * 16;
            cv0 = *reinterpret_cast<const uint4*>(vp);
            cv1 = *reinterpret_cast<const uint4*>(vp + 8);
        }

        floatx16 st = {};
        const unsigned int* kr = &smem[rb + (32 * kh + l31) * 32];
        const int esw = l31 & 7;
        __builtin_amdgcn_s_setprio(1);
        #pragma unroll
        for (int kc = 0; kc < 4; ++kc) {
            union { uint4 v; short8 s8; } af;
            af.v = *reinterpret_cast<const uint4*>(&kr[((2 * kc + h) ^ esw) << 2]);
            st = __builtin_amdgcn_mfma_f32_32x32x16_bf16(af.s8, bq[kc], st, 0, 0, 0);
        }
        __builtin_amdgcn_s_setprio(0);

        float p[16];
        float rs0 = 0.f, rs1 = 0.f, rs2 = 0.f, rs3 = 0.f;
        #pragma unroll
        for (int r = 0; r < 16; r += 4) {
            p[r]     = fast_exp2(st[r]);     rs0 += p[r];
            p[r + 1] = fast_exp2(st[r + 1]); rs1 += p[r + 1];
            p[r + 2] = fast_exp2(st[r + 2]); rs2 += p[r + 2];
            p[r + 3] = fast_exp2(st[r + 3]); rs3 += p[r + 3];
        }
        float rs = (rs0 + rs1) + (rs2 + rs3);
        rs += __shfl_xor(rs, 32);
        l_i += rs;

        unsigned int pk[8], sp[8];
        #pragma unroll
        for (int i = 0; i < 8; ++i) pk[i] = f2bf_pk(p[2 * i], p[2 * i + 1]);
        #pragma unroll
        for (int i = 0; i < 8; ++i) sp[i] = (unsigned int)__shfl_xor((int)pk[i], 32);
        union { unsigned int u[4]; short8 s8; } pb0, pb1;
        pb0.u[0] = h ? sp[2] : pk[0]; pb0.u[1] = h ? sp[3] : pk[1];
        pb0.u[2] = h ? pk[2] : sp[0]; pb0.u[3] = h ? pk[3] : sp[1];
        pb1.u[0] = h ? sp[6] : pk[4]; pb1.u[1] = h ? sp[7] : pk[5];
        pb1.u[2] = h ? pk[6] : sp[4]; pb1.u[3] = h ? pk[7] : sp[5];

        const unsigned int* vr0 = &smem[rb + 2048 + l31 * 32];
        const unsigned int* vr1 = &smem[rb + 2048 + (32 + l31) * 32];
        __builtin_amdgcn_s_setprio(1);
        #pragma unroll
        for (int c = 0; c < 2; ++c) {
            union { uint4 v; short8 s8; } af;
            af.v = *reinterpret_cast<const uint4*>(&vr0[((4 * kh + 2 * c + h) ^ esw) << 2]);
            ot0 = __builtin_amdgcn_mfma_f32_32x32x16_bf16(af.s8, c ? pb1.s8 : pb0.s8, ot0, 0, 0, 0);
            af.v = *reinterpret_cast<const uint4*>(&vr1[((4 * kh + 2 * c + h) ^ esw) << 2]);
            ot1 = __builtin_amdgcn_mfma_f32_32x32x16_bf16(af.s8, c ? pb1.s8 : pb0.s8, ot1, 0, 0, 0);
        }
        __builtin_amdgcn_s_setprio(0);
    }

    // ---- merge kh halves: pure sums ----
    __syncthreads();
    if (h == 0) smem[8192 + w * 32 + l31] = __float_as_uint(l_i);
    __syncthreads();
    int pw = 2 * (1 - kh) + qh;
    float l2 = __uint_as_float(smem[8192 + pw * 32 + l31]);
    float lm = l_i + l2;
    float sc = (gridDim.z == 1) ? (1.0f / lm) : 1.0f;
    if (gridDim.z > 1 && kh == 0 && h == 0) {
        float2 v; v.x = 0.f; v.y = lm;
        ml[((size_t)s * 4 + b) * 4096 + n0 + 32 * qh + l31] = v;
    }
    float* om = reinterpret_cast<float*>(smem);
    if (kh == 0) {
        #pragma unroll
        for (int r = 0; r < 16; ++r) {
            int d0 = (r & 3) + 8 * (r >> 2) + 4 * h;
            om[(32 * qh + l31) * 65 + d0] = sc * ot0[r];
            om[(32 * qh + l31) * 65 + 32 + d0] = sc * ot1[r];
        }
    }
    __syncthreads();
    if (kh == 1) {
        #pragma unroll
        for (int r = 0; r < 16; ++r) {
            int d0 = (r & 3) + 8 * (r >> 2) + 4 * h;
            om[(32 * qh + l31) * 65 + d0] += sc * ot0[r];
            om[(32 * qh + l31) * 65 + 32 + d0] += sc * ot1[r];
        }
    }
    __syncthreads();
    {
        int qq = tid >> 2, dsg = tid & 3;
        unsigned int pkk[8];
        #pragma unroll
        for (int j = 0; j < 8; ++j)
            pkk[j] = f2bf_pk(om[qq * 65 + dsg * 16 + 2 * j], om[qq * 65 + dsg * 16 + 2 * j + 1]);
        ushortt* base = (gridDim.z == 1)
            ? (Ob + ((size_t)b * 4096 + n0) * 64)
            : (Opart + (((size_t)s * 4 + b) * 4096 + n0) * 64);
        uint4* d4 = reinterpret_cast<uint4*>(base + (size_t)qq * 64 + dsg * 16);
        uint4 o0; o0.x = pkk[0]; o0.y = pkk[1]; o0.z = pkk[2]; o0.w = pkk[3];
        uint4 o1; o1.x = pkk[4]; o1.y = pkk[5]; o1.z = pkk[6]; o1.w = pkk[7];
        d4[0] = o0; d4[1] = o1;
    }
}

// ---------------------------------------------------------------------------
// Fused combine + output projection. S==2: wvb is UNSCALED -> scale the
// accumulator by 1/sig[3] in the epilogue (R8-validated). S==1 fallback:
// wvb pre-scaled, no epilogue scaling.
// ---------------------------------------------------------------------------
template <int S>
__global__ __launch_bounds__(256, 3) void proj_kernel(
    const ushortt* __restrict__ Opart, const float2* __restrict__ ml,
    const ushortt* __restrict__ Ob, const ushortt* __restrict__ wvb,
    const float* __restrict__ bv, const float* __restrict__ gamma,
    const float* __restrict__ sig,
    const float* __restrict__ x, float* __restrict__ out) {
    __shared__ ushortt ol[32 * 72];
    const int tid = threadIdx.x;
    const int n0 = blockIdx.x * 32, b = blockIdx.y;

    {   // combine (raw sums) or plain load into LDS
        int row = tid >> 3, t8 = tid & 7;
        int rg = n0 + row;
        if (S == 1) {
            uint4 v = *reinterpret_cast<const uint4*>(
                Ob + ((size_t)b * 4096 + rg) * 64 + t8 * 8);
            *reinterpret_cast<uint4*>(&ol[row * 72 + t8 * 8]) = v;
        } else {
            float denom = 0.f;
            #pragma unroll
            for (int s2 = 0; s2 < S; ++s2)
                denom += ml[((size_t)s2 * 4 + b) * 4096 + rg].y;
            float inv = 1.0f / denom;
            float acc8[8];
            #pragma unroll
            for (int j = 0; j < 8; ++j) acc8[j] = 0.f;
            #pragma unroll
            for (int s2 = 0; s2 < S; ++s2) {
                union { uint4 v; ushortt hh[8]; } u;
                u.v = *reinterpret_cast<const uint4*>(
                    Opart + (((size_t)s2 * 4 + b) * 4096 + rg) * 64 + t8 * 8);
                #pragma unroll
                for (int j = 0; j < 8; ++j) acc8[j] += bf2f(u.hh[j]);
            }
            uint4 v;
            v.x = f2bf_pk(acc8[0] * inv, acc8[1] * inv);
            v.y = f2bf_pk(acc8[2] * inv, acc8[3] * inv);
            v.z = f2bf_pk(acc8[4] * inv, acc8[5] * inv);
            v.w = f2bf_pk(acc8[6] * inv, acc8[7] * inv);
            *reinterpret_cast<uint4*>(&ol[row * 72 + t8 * 8]) = v;
        }
    }
    __syncthreads();

    const int w = tid >> 6, lane = tid & 63, q = lane >> 4, l15 = lane & 15;
    short8 bfr[2][2];
    #pragma unroll
    for (int u = 0; u < 2; ++u)
        #pragma unroll
        for (int kc = 0; kc < 2; ++kc)
            bfr[u][kc] = *reinterpret_cast<const short8*>(
                &ol[(16 * u + l15) * 72 + 32 * kc + q * 8]);

    floatx4 acc[8][2];
    #pragma unroll
    for (int t = 0; t < 8; ++t)
        #pragma unroll
        for (int u = 0; u < 2; ++u) acc[t][u] = (floatx4){0.f, 0.f, 0.f, 0.f};

    const int cw = w * 128;
    #pragma unroll
    for (int t = 0; t < 8; ++t) {
        short8 a0 = *reinterpret_cast<const short8*>(
            &wvb[(size_t)(cw + 16 * t + l15) * 64 + q * 8]);
        short8 a1 = *reinterpret_cast<const short8*>(
            &wvb[(size_t)(cw + 16 * t + l15) * 64 + 32 + q * 8]);
        #pragma unroll
        for (int u = 0; u < 2; ++u) {
            acc[t][u] = __builtin_amdgcn_mfma_f32_16x16x32_bf16(a0, bfr[u][0], acc[t][u], 0, 0, 0);
            acc[t][u] = __builtin_amdgcn_mfma_f32_16x16x32_bf16(a1, bfr[u][1], acc[t][u], 0, 0, 0);
        }
    }

    float gm = gamma[0];
    float inv3 = (S == 2) ? (1.0f / sig[3]) : 1.0f;
    #pragma unroll
    for (int t = 0; t < 8; ++t) {
        #pragma unroll
        for (int r = 0; r < 4; ++r) {
            int c = cw + 16 * t + 4 * q + r;
            float bb = bv[c];
            #pragma unroll
            for (int u = 0; u < 2; ++u) {
                int n = n0 + 16 * u + l15;
                size_t idx = ((size_t)(b * 512 + c)) * 4096 + n;
                out[idx] = gm * (acc[t][u][r] * inv3 + bb) + x[idx];
            }
        }
    }
}

// ===========================================================================
// Fallback kernels (ws too small for flags): verified R7 path, S=1.
// ===========================================================================
__global__ __launch_bounds__(256) void sigma_kernel(
    const float* __restrict__ Wf, const float* __restrict__ uf,
    const float* __restrict__ Wg, const float* __restrict__ ug,
    const float* __restrict__ Wh, const float* __restrict__ uh,
    const float* __restrict__ Wv, const float* __restrict__ uv,
    float* __restrict__ sig,
    ushortt* __restrict__ wqkv, ushortt* __restrict__ wvb) {
    __shared__ float tv[512];
    __shared__ float tvp[256];
    __shared__ float zpart[256];
    __shared__ float red[4];
    __shared__ float ssig;
    const int mat = blockIdx.x, tid = threadIdx.x;

    if (mat < 3) {
        const float* W = (mat == 0) ? Wf : ((mat == 1) ? Wg : Wh);
        const float* u = (mat == 0) ? uf : ((mat == 1) ? ug : uh);
        {
            float s0 = 0.f, s1 = 0.f;
            #pragma unroll 8
            for (int r = 0; r < 64; ++r) {
                float ur = u[r];
                s0 += W[r * 512 + tid] * ur;
                s1 += W[r * 512 + tid + 256] * ur;
            }
            tv[tid] = s0;
            tv[tid + 256] = s1;
        }
        __syncthreads();
        float p = tv[tid] * tv[tid] + tv[tid + 256] * tv[tid + 256];
        float nt2 = block_sum(p, red);
        float nt = fmaxf(sqrtf(nt2), 1e-12f);
        {
            int r = tid & 63, qq = tid >> 6;
            const float* Wr = W + r * 512 + qq * 128;
            const float* tq = tv + qq * 128;
            float part = 0.f;
            #pragma unroll 16
            for (int c = 0; c < 128; ++c) part += Wr[c] * tq[c];
            zpart[tid] = part;
        }
        __syncthreads();
        if (tid < 64) {
            float z = zpart[tid] + zpart[tid + 64] + zpart[tid + 128] + zpart[tid + 192];
            z = z * z;
            #pragma unroll
            for (int off = 32; off > 0; off >>= 1) z += __shfl_xor(z, off);
            if (tid == 0) {
                float sg0 = sqrtf(z) / nt;
                sig[mat] = sg0;
                ssig = sg0;
            }
        }
        __syncthreads();
        float inv = 1.0f / ssig;
        const float4* W4 = reinterpret_cast<const float4*>(W);
        unsigned int* dst = reinterpret_cast<unsigned int*>(wqkv + mat * 32768);
        for (int i = tid; i < 8192; i += 256) {
            float4 wv = W4[i];
            dst[2 * i]     = f2bf_pk(wv.x * inv, wv.y * inv);
            dst[2 * i + 1] = f2bf_pk(wv.z * inv, wv.w * inv);
        }
    } else {
        const float* W = Wv; const float* u = uv;
        {
            int c = tid & 63, rs = tid >> 6;
            float s0 = 0.f;
            #pragma unroll 8
            for (int r = rs * 128; r < rs * 128 + 128; ++r) s0 += W[r * 64 + c] * u[r];
            tvp[tid] = s0;
        }
        __syncthreads();
        if (tid < 64) tv[tid] = tvp[tid] + tvp[tid + 64] + tvp[tid + 128] + tvp[tid + 192];
        __syncthreads();
        float t = (tid < 64) ? tv[tid] : 0.f;
        float nt2 = block_sum(t * t, red);
        float nt = fmaxf(sqrtf(nt2), 1e-12f);
        float sg3;
        {
            const float* w1 = W + (size_t)tid * 64;
            const float* w2 = W + (size_t)(tid + 256) * 64;
            float z1 = 0.f, z2 = 0.f;
            #pragma unroll 8
            for (int c = 0; c < 64; ++c) {
                float tc = tv[c];
                z1 += w1[c] * tc;
                z2 += w2[c] * tc;
            }
            float zp = z1 * z1 + z2 * z2;
            float z2t = block_sum(zp, red);
            sg3 = sqrtf(z2t) / nt;
            if (tid == 0) sig[3] = sg3;
        }
        float inv = 1.0f / sg3;
        const float4* W4 = reinterpret_cast<const float4*>(W);
        unsigned int* dst = reinterpret_cast<unsigned int*>(wvb);
        for (int i = tid; i < 8192; i += 256) {
            float4 wv = W4[i];
            dst[2 * i]     = f2bf_pk(wv.x * inv, wv.y * inv);
            dst[2 * i + 1] = f2bf_pk(wv.z * inv, wv.w * inv);
        }
    }
}

__global__ __launch_bounds__(256, 3) void qkv_kernel(
    const float* __restrict__ x, const ushortt* __restrict__ wqkv,
    const float* __restrict__ bfv, const float* __restrict__ bgv,
    const float* __restrict__ bhv,
    ushortt* __restrict__ Qb, ushortt* __restrict__ Kb, ushortt* __restrict__ Vt) {
    __shared__ unsigned int xs[2048];
    const int tid = threadIdx.x;
    const int n0 = blockIdx.x * 32, b = blockIdx.y;
    const int lane = tid & 63, w = tid >> 6;
    const int strip = w & 1, ksel = w >> 1;
    const int q = lane >> 4, l15 = lane & 15;
    const int sn = tid & 31, sg = tid >> 5;

    floatx4 acc[6];
    #pragma unroll
    for (int kt = 0; kt < 6; ++kt) acc[kt] = (floatx4){0.f, 0.f, 0.f, 0.f};

    const float* xb = x + ((size_t)b * 512) * 4096 + n0 + sn;
    const int sslot = sn * 32 + ((sg ^ (sn & 7)) << 2);
    float2 pre[4];
    #pragma unroll
    for (int i = 0; i < 4; ++i) {
        int c = sg * 8 + 2 * i;
        pre[i].x = xb[(size_t)c * 4096];
        pre[i].y = xb[(size_t)(c + 1) * 4096];
    }
    {
        uint4 pk;
        pk.x = f2bf_pk(pre[0].x, pre[0].y);
        pk.y = f2bf_pk(pre[1].x, pre[1].y);
        pk.z = f2bf_pk(pre[2].x, pre[2].y);
        pk.w = f2bf_pk(pre[3].x, pre[3].y);
        *reinterpret_cast<uint4*>(&xs[sslot]) = pk;
    }
    #pragma unroll
    for (int i = 0; i < 4; ++i) {
        int c = 64 + sg * 8 + 2 * i;
        pre[i].x = xb[(size_t)c * 4096];
        pre[i].y = xb[(size_t)(c + 1) * 4096];
    }

    for (int it = 0; it < 8; ++it) {
        __syncthreads();
        if (it < 7) {
            uint4 pk;
            pk.x = f2bf_pk(pre[0].x, pre[0].y);
            pk.y = f2bf_pk(pre[1].x, pre[1].y);
            pk.z = f2bf_pk(pre[2].x, pre[2].y);
            pk.w = f2bf_pk(pre[3].x, pre[3].y);
            *reinterpret_cast<uint4*>(&xs[(((it + 1) & 1) << 10) + sslot]) = pk;
        }
        if (it < 6) {
            #pragma unroll
            for (int i = 0; i < 4; ++i) {
                int c = (it + 2) * 64 + sg * 8 + 2 * i;
                pre[i].x = xb[(size_t)c * 4096];
                pre[i].y = xb[(size_t)(c + 1) * 4096];
            }
        }
        const int c0 = it * 64;
        const unsigned int* xr = &xs[((it & 1) << 10) + (16 * strip + l15) * 32];
        #pragma unroll
        for (int kc = 0; kc < 2; ++kc) {
            union { uint4 v; short8 s8; } af;
            af.v = *reinterpret_cast<const uint4*>(&xr[((4 * kc + q) ^ (l15 & 7)) << 2]);
            #pragma unroll
            for (int kt = 0; kt < 6; ++kt) {
                short8 bb = *reinterpret_cast<const short8*>(
                    &wqkv[(size_t)(ksel * 96 + kt * 16 + l15) * 512 + c0 + kc * 32 + q * 8]);
                acc[kt] = __builtin_amdgcn_mfma_f32_16x16x32_bf16(af.s8, bb, acc[kt], 0, 0, 0);
            }
        }
    }

    const int nloc = n0 + 16 * strip + 4 * q;
    if (ksel == 0) {
        #pragma unroll
        for (int kt = 0; kt < 4; ++kt) {
            int k = kt * 16 + l15;
            float bb = bfv[k];
            #pragma unroll
            for (int r = 0; r < 4; ++r)
                Qb[((size_t)b * 4096 + nloc + r) * 64 + k] = f2bf((acc[kt][r] + bb) * LOG2E);
        }
        #pragma unroll
        for (int kt = 4; kt < 6; ++kt) {
            int k = (kt - 4) * 16 + l15;
            float bb = bgv[k];
            #pragma unroll
            for (int r = 0; r < 4; ++r)
                Kb[((size_t)b * 4096 + nloc + r) * 64 + k] = f2bf(acc[kt][r] + bb);
        }
    } else {
        #pragma unroll
        for (int kt = 0; kt < 2; ++kt) {
            int k = 32 + kt * 16 + l15;
            float bb = bgv[k];
            #pragma unroll
            for (int r = 0; r < 4; ++r)
                Kb[((size_t)b * 4096 + nloc + r) * 64 + k] = f2bf(acc[kt][r] + bb);
        }
    }
    __syncthreads();
    if (ksel == 1) {
        #pragma unroll
        for (int kt = 2; kt < 6; ++kt) {
            int d = (kt - 2) * 16 + l15;
            float bb = bhv[d];
            int base = d * 17 + 8 * strip + 2 * q;
            xs[base]     = f2bf_pk(acc[kt][0] + bb, acc[kt][1] + bb);
            xs[base + 1] = f2bf_pk(acc[kt][2] + bb, acc[kt][3] + bb);
        }
    }
    __syncthreads();
    {
        int d = tid >> 2, sgg = tid & 3;
        uint4 vv;
        vv.x = xs[d * 17 + sgg * 4 + 0]; vv.y = xs[d * 17 + sgg * 4 + 1];
        vv.z = xs[d * 17 + sgg * 4 + 2]; vv.w = xs[d * 17 + sgg * 4 + 3];
        *reinterpret_cast<uint4*>(&Vt[((size_t)b * 64 + d) * 4096 + n0 + sgg * 8]) = vv;
    }
}

// ---------------------------------------------------------------------------
extern "C" void kernel_launch(void* const* d_in, const int* in_sizes, int n_in,
                              void* d_out, int out_size, void* d_ws, size_t ws_size,
                              hipStream_t stream) {
    const float* x   = (const float*)d_in[0];
    const float* Wf  = (const float*)d_in[1];
    const float* bf_ = (const float*)d_in[2];
    const float* Wg  = (const float*)d_in[3];
    const float* bg_ = (const float*)d_in[4];
    const float* Wh  = (const float*)d_in[5];
    const float* bh_ = (const float*)d_in[6];
    const float* Wv  = (const float*)d_in[7];
    const float* bv_ = (const float*)d_in[8];
    const float* uf  = (const float*)d_in[9];
    const float* ug  = (const float*)d_in[10];
    const float* uh  = (const float*)d_in[11];
    const float* uv  = (const float*)d_in[12];
    const float* gm  = (const float*)d_in[13];
    float* out = (float*)d_out;

    char* ws = (char*)d_ws;
    float*   sig   = (float*)ws;                         // 256 B
    ushortt* wqkv  = (ushortt*)(ws + 256);               // 196608
    ushortt* wvb   = (ushortt*)(ws + 196864);            // 65536
    ushortt* Qb    = (ushortt*)(ws + 262400);            // 2 MB
    ushortt* Kb    = (ushortt*)(ws + 2359552);           // 2 MB
    ushortt* Vt    = (ushortt*)(ws + 4456704);           // 2 MB  [b][d][n]
    ushortt* Ob    = (ushortt*)(ws + 6553856);           // 2 MB (fallback)
    float2*  ml    = (float2*)(ws + 8651008);            // 512 KB
    ushortt* Opart = (ushortt*)(ws + 9175296);           // 4 MB bf16 (S=2)
    unsigned int* fl_conv = (unsigned int*)(ws + 13369600);  // 4 dw
    unsigned int* fl_sig  = fl_conv + 4;                     // 4 dw

    if (ws_size >= (size_t)13369700) {
        qkv_fused_kernel<<<520, 256, 0, stream>>>(
            x, Wf, bf_, Wg, bg_, Wh, bh_, Wv, uf, ug, uh, uv,
            sig, wqkv, wvb, Qb, Kb, Vt, fl_conv, fl_sig);
        attn_kernel<<<dim3(64, 4, 2), 256, 0, stream>>>(Qb, Kb, Vt, Opart, ml, Ob, 32);
        proj_kernel<2><<<dim3(128, 4), 256, 0, stream>>>(
            Opart, ml, Ob, wvb, bv_, gm, sig, x, out);
    } else {
        sigma_kernel<<<4, 256, 0, stream>>>(Wf, uf, Wg, ug, Wh, uh, Wv, uv, sig, wqkv, wvb);
        qkv_kernel<<<dim3(128, 4), 256, 0, stream>>>(x, wqkv, bf_, bg_, bh_, Qb, Kb, Vt);
        attn_kernel<<<dim3(64, 4, 1), 256, 0, stream>>>(Qb, Kb, Vt, Opart, ml, Ob, 64);
        proj_kernel<1><<<dim3(128, 4), 256, 0, stream>>>(
            Opart, ml, Ob, wvb, bv_, gm, sig, x, out);
    }
}

// Round 10
// 186.521 us; speedup vs baseline: 1.9717x; 1.3205x over previous
//
#include <hip/hip_runtime.h>
#include <hip/hip_bf16.h>

typedef __attribute__((ext_vector_type(8))) short short8;
typedef __attribute__((ext_vector_type(4))) float floatx4;
typedef __attribute__((ext_vector_type(16))) float floatx16;
typedef unsigned short ushortt;

#define LOG2E 1.4426950408889634f

__device__ __forceinline__ float fast_exp2(float x) {
    return __builtin_amdgcn_exp2f(x);      // raw v_exp_f32
}
__device__ __forceinline__ ushortt f2bf(float f) {
    unsigned int u = __float_as_uint(f);
    u += 0x7fffu + ((u >> 16) & 1u);
    return (ushortt)(u >> 16);
}
__device__ __forceinline__ unsigned int f2bf_pk(float a, float b) {
    float2 t; t.x = a; t.y = b;
    __hip_bfloat162 h = __float22bfloat162_rn(t);
    return *reinterpret_cast<unsigned int*>(&h);
}
__device__ __forceinline__ float bf2f(ushortt h) {
    return __uint_as_float(((unsigned int)h) << 16);
}

__device__ __forceinline__ float block_sum(float v, float* red) {
    #pragma unroll
    for (int off = 32; off > 0; off >>= 1) v += __shfl_down(v, off);
    int wid = threadIdx.x >> 6, ln = threadIdx.x & 63;
    __syncthreads();
    if (ln == 0) red[wid] = v;
    __syncthreads();
    return red[0] + red[1] + red[2] + red[3];
}

// ---------------------------------------------------------------------------
// sigma = ||W @ normalize(W^T u)|| fused with bf16 weight conversion.
// (Revert to round-5 source: best measured configuration, 187.7 us.)
// ---------------------------------------------------------------------------
__global__ __launch_bounds__(256) void sigma_kernel(
    const float* __restrict__ Wf, const float* __restrict__ uf,
    const float* __restrict__ Wg, const float* __restrict__ ug,
    const float* __restrict__ Wh, const float* __restrict__ uh,
    const float* __restrict__ Wv, const float* __restrict__ uv,
    float* __restrict__ sig,
    ushortt* __restrict__ wqkv, ushortt* __restrict__ wvb) {
    __shared__ float tv[512];
    __shared__ float tvp[256];
    __shared__ float zpart[256];
    __shared__ float red[4];
    __shared__ float ssig;
    const int mat = blockIdx.x, tid = threadIdx.x;

    if (mat < 3) {  // W: [64][512]
        const float* W = (mat == 0) ? Wf : ((mat == 1) ? Wg : Wh);
        const float* u = (mat == 0) ? uf : ((mat == 1) ? ug : uh);
        {   // phase 1: tv = W^T u, both columns in one loop (2x ILP)
            float s0 = 0.f, s1 = 0.f;
            #pragma unroll 8
            for (int r = 0; r < 64; ++r) {
                float ur = u[r];
                s0 += W[r * 512 + tid] * ur;
                s1 += W[r * 512 + tid + 256] * ur;
            }
            tv[tid] = s0;
            tv[tid + 256] = s1;
        }
        __syncthreads();
        float p = tv[tid] * tv[tid] + tv[tid + 256] * tv[tid + 256];
        float nt2 = block_sum(p, red);
        float nt = fmaxf(sqrtf(nt2), 1e-12f);
        {
            int r = tid & 63, qq = tid >> 6;
            const float* Wr = W + r * 512 + qq * 128;
            const float* tq = tv + qq * 128;
            float part = 0.f;
            #pragma unroll 16
            for (int c = 0; c < 128; ++c) part += Wr[c] * tq[c];
            zpart[tid] = part;
        }
        __syncthreads();
        if (tid < 64) {
            float z = zpart[tid] + zpart[tid + 64] + zpart[tid + 128] + zpart[tid + 192];
            z = z * z;
            #pragma unroll
            for (int off = 32; off > 0; off >>= 1) z += __shfl_xor(z, off);
            if (tid == 0) {
                float sg0 = sqrtf(z) / nt;
                sig[mat] = sg0;
                ssig = sg0;
            }
        }
        __syncthreads();
        float inv = 1.0f / ssig;
        const float4* W4 = reinterpret_cast<const float4*>(W);
        unsigned int* dst = reinterpret_cast<unsigned int*>(wqkv + mat * 32768);
        for (int i = tid; i < 8192; i += 256) {
            float4 wv = W4[i];
            dst[2 * i]     = f2bf_pk(wv.x * inv, wv.y * inv);
            dst[2 * i + 1] = f2bf_pk(wv.z * inv, wv.w * inv);
        }
    } else {        // Wv: [512][64]
        const float* W = Wv; const float* u = uv;
        {
            int c = tid & 63, rs = tid >> 6;
            float s0 = 0.f;
            #pragma unroll 8
            for (int r = rs * 128; r < rs * 128 + 128; ++r) s0 += W[r * 64 + c] * u[r];
            tvp[tid] = s0;
        }
        __syncthreads();
        if (tid < 64) tv[tid] = tvp[tid] + tvp[tid + 64] + tvp[tid + 128] + tvp[tid + 192];
        __syncthreads();
        float t = (tid < 64) ? tv[tid] : 0.f;
        float nt2 = block_sum(t * t, red);
        float nt = fmaxf(sqrtf(nt2), 1e-12f);
        float sg3;
        {
            const float* w1 = W + (size_t)tid * 64;
            const float* w2 = W + (size_t)(tid + 256) * 64;
            float z1 = 0.f, z2 = 0.f;
            #pragma unroll 8
            for (int c = 0; c < 64; ++c) {
                float tc = tv[c];
                z1 += w1[c] * tc;
                z2 += w2[c] * tc;
            }
            float zp = z1 * z1 + z2 * z2;
            float z2t = block_sum(zp, red);
            sg3 = sqrtf(z2t) / nt;
            if (tid == 0) sig[3] = sg3;
        }
        float inv = 1.0f / sg3;
        const float4* W4 = reinterpret_cast<const float4*>(W);
        unsigned int* dst = reinterpret_cast<unsigned int*>(wvb);
        for (int i = tid; i < 8192; i += 256) {
            float4 wv = W4[i];
            dst[2 * i]     = f2bf_pk(wv.x * inv, wv.y * inv);
            dst[2 * i + 1] = f2bf_pk(wv.z * inv, wv.w * inv);
        }
    }
}

// ---------------------------------------------------------------------------
// QKV projection, 32-pixel tiles. XOR-swizzled LDS, double-buffered, one
// barrier per 64-channel step. Q pre-scaled by LOG2E. V stored Vt[b][d][n].
// ---------------------------------------------------------------------------
__global__ __launch_bounds__(256, 3) void qkv_kernel(
    const float* __restrict__ x, const ushortt* __restrict__ wqkv,
    const float* __restrict__ bfv, const float* __restrict__ bgv,
    const float* __restrict__ bhv,
    ushortt* __restrict__ Qb, ushortt* __restrict__ Kb, ushortt* __restrict__ Vt) {
    __shared__ unsigned int xs[2048];          // 2 x (32 rows x 32 dwords)
    const int tid = threadIdx.x;
    const int n0 = blockIdx.x * 32, b = blockIdx.y;
    const int lane = tid & 63, w = tid >> 6;
    const int strip = w & 1, ksel = w >> 1;
    const int q = lane >> 4, l15 = lane & 15;
    const int sn = tid & 31, sg = tid >> 5;

    floatx4 acc[6];
    #pragma unroll
    for (int kt = 0; kt < 6; ++kt) acc[kt] = (floatx4){0.f, 0.f, 0.f, 0.f};

    const float* xb = x + ((size_t)b * 512) * 4096 + n0 + sn;
    const int sslot = sn * 32 + ((sg ^ (sn & 7)) << 2);
    float2 pre[4];
    #pragma unroll
    for (int i = 0; i < 4; ++i) {
        int c = sg * 8 + 2 * i;
        pre[i].x = xb[(size_t)c * 4096];
        pre[i].y = xb[(size_t)(c + 1) * 4096];
    }
    {
        uint4 pk;
        pk.x = f2bf_pk(pre[0].x, pre[0].y);
        pk.y = f2bf_pk(pre[1].x, pre[1].y);
        pk.z = f2bf_pk(pre[2].x, pre[2].y);
        pk.w = f2bf_pk(pre[3].x, pre[3].y);
        *reinterpret_cast<uint4*>(&xs[sslot]) = pk;
    }
    #pragma unroll
    for (int i = 0; i < 4; ++i) {
        int c = 64 + sg * 8 + 2 * i;
        pre[i].x = xb[(size_t)c * 4096];
        pre[i].y = xb[(size_t)(c + 1) * 4096];
    }

    for (int it = 0; it < 8; ++it) {
        __syncthreads();
        if (it < 7) {
            uint4 pk;
            pk.x = f2bf_pk(pre[0].x, pre[0].y);
            pk.y = f2bf_pk(pre[1].x, pre[1].y);
            pk.z = f2bf_pk(pre[2].x, pre[2].y);
            pk.w = f2bf_pk(pre[3].x, pre[3].y);
            *reinterpret_cast<uint4*>(&xs[(((it + 1) & 1) << 10) + sslot]) = pk;
        }
        if (it < 6) {
            #pragma unroll
            for (int i = 0; i < 4; ++i) {
                int c = (it + 2) * 64 + sg * 8 + 2 * i;
                pre[i].x = xb[(size_t)c * 4096];
                pre[i].y = xb[(size_t)(c + 1) * 4096];
            }
        }
        const int c0 = it * 64;
        const unsigned int* xr = &xs[((it & 1) << 10) + (16 * strip + l15) * 32];
        #pragma unroll
        for (int kc = 0; kc < 2; ++kc) {
            union { uint4 v; short8 s8; } af;
            af.v = *reinterpret_cast<const uint4*>(&xr[((4 * kc + q) ^ (l15 & 7)) << 2]);
            #pragma unroll
            for (int kt = 0; kt < 6; ++kt) {
                short8 bb = *reinterpret_cast<const short8*>(
                    &wqkv[(size_t)(ksel * 96 + kt * 16 + l15) * 512 + c0 + kc * 32 + q * 8]);
                acc[kt] = __builtin_amdgcn_mfma_f32_16x16x32_bf16(af.s8, bb, acc[kt], 0, 0, 0);
            }
        }
    }

    const int nloc = n0 + 16 * strip + 4 * q;
    if (ksel == 0) {
        #pragma unroll
        for (int kt = 0; kt < 4; ++kt) {       // Q (exp2-domain)
            int k = kt * 16 + l15;
            float bb = bfv[k];
            #pragma unroll
            for (int r = 0; r < 4; ++r)
                Qb[((size_t)b * 4096 + nloc + r) * 64 + k] = f2bf((acc[kt][r] + bb) * LOG2E);
        }
        #pragma unroll
        for (int kt = 4; kt < 6; ++kt) {       // K rows 0..31
            int k = (kt - 4) * 16 + l15;
            float bb = bgv[k];
            #pragma unroll
            for (int r = 0; r < 4; ++r)
                Kb[((size_t)b * 4096 + nloc + r) * 64 + k] = f2bf(acc[kt][r] + bb);
        }
    } else {
        #pragma unroll
        for (int kt = 0; kt < 2; ++kt) {       // K rows 32..63
            int k = 32 + kt * 16 + l15;
            float bb = bgv[k];
            #pragma unroll
            for (int r = 0; r < 4; ++r)
                Kb[((size_t)b * 4096 + nloc + r) * 64 + k] = f2bf(acc[kt][r] + bb);
        }
    }
    __syncthreads();
    if (ksel == 1) {                           // V -> LDS [d][n/2] (stride 17 dwords)
        #pragma unroll
        for (int kt = 2; kt < 6; ++kt) {
            int d = (kt - 2) * 16 + l15;
            float bb = bhv[d];
            int base = d * 17 + 8 * strip + 2 * q;
            xs[base]     = f2bf_pk(acc[kt][0] + bb, acc[kt][1] + bb);
            xs[base + 1] = f2bf_pk(acc[kt][2] + bb, acc[kt][3] + bb);
        }
    }
    __syncthreads();
    {
        int d = tid >> 2, sgg = tid & 3;
        uint4 vv;
        vv.x = xs[d * 17 + sgg * 4 + 0]; vv.y = xs[d * 17 + sgg * 4 + 1];
        vv.z = xs[d * 17 + sgg * 4 + 2]; vv.w = xs[d * 17 + sgg * 4 + 3];
        *reinterpret_cast<uint4*>(&Vt[((size_t)b * 64 + d) * 4096 + n0 + sgg * 8]) = vv;
    }
}

// ---------------------------------------------------------------------------
// Flash attention, 32x32x16 MFMA, XOR-swizzled b128 LDS, v_exp_f32 softmax.
// Double-buffered K/V tiles, ONE barrier per KV-step, defer-max (THR=8).
// XCD-aware bijective block mapping; s_setprio(1) around MFMA clusters.
// launch_bounds(256,3): ~168 VGPR cap -> no spills; LDS 33.8KB x3 = 101KB.
// ---------------------------------------------------------------------------
__global__ __launch_bounds__(256, 3) void attn_kernel(
    const ushortt* __restrict__ Qb, const ushortt* __restrict__ Kb,
    const ushortt* __restrict__ Vt, ushortt* __restrict__ Opart,
    float2* __restrict__ ml, ushortt* __restrict__ Ob, int KB) {
    __shared__ unsigned int smem[8448];        // 2 x 4096 dbuf + 256 m/l
    const int tid = threadIdx.x;
    int n0, b, s;
    if (gridDim.z == 4) {
        int fid = blockIdx.x + 64 * blockIdx.y + 256 * blockIdx.z;
        int xcd = fid & 7, idx = fid >> 3;
        b = xcd >> 1;                           // 2 XCDs per batch
        int within = ((xcd & 1) << 7) + idx;    // [0,256): 64 n-tiles x 4 s
        s = within >> 6;
        n0 = (within & 63) * 64;
    } else {
        n0 = blockIdx.x * 64; b = blockIdx.y; s = blockIdx.z;
    }
    const int lane = tid & 63, w = tid >> 6;
    const int qh = w & 1, kh = w >> 1;
    const int l31 = lane & 31, h = lane >> 5;

    const ushortt* Kg = Kb + (size_t)b * 4096 * 64;
    const ushortt* Vg = Vt + (size_t)b * 64 * 4096;

    short8 bq[4];
    {
        const ushortt* Qg = Qb + ((size_t)b * 4096 + n0 + 32 * qh + l31) * 64;
        #pragma unroll
        for (int kc = 0; kc < 4; ++kc)
            bq[kc] = *reinterpret_cast<const short8*>(Qg + kc * 16 + 8 * h);
    }

    floatx16 ot0 = {}, ot1 = {};
    float m_i = -1e30f, l_i = 0.f;

    const int row = tid >> 2, seg = tid & 3;
    const int kbeg = s * KB, kend = kbeg + KB;
    const int rsw = row & 7;
    const int ws0 = row * 32 + ((((2 * seg)) ^ rsw) << 2);
    const int ws1 = row * 32 + ((((2 * seg + 1)) ^ rsw) << 2);

    uint4 ck0, ck1, cv0, cv1;
    {   // tile kbeg -> regs
        int nb = kbeg * 64;
        const ushortt* kp = Kg + (size_t)(nb + row) * 64 + seg * 16;
        ck0 = *reinterpret_cast<const uint4*>(kp);
        ck1 = *reinterpret_cast<const uint4*>(kp + 8);
        const ushortt* vp = Vg + (size_t)row * 4096 + nb + seg * 16;
        cv0 = *reinterpret_cast<const uint4*>(vp);
        cv1 = *reinterpret_cast<const uint4*>(vp + 8);
    }
    // write buf0
    *reinterpret_cast<uint4*>(&smem[ws0]) = ck0;
    *reinterpret_cast<uint4*>(&smem[ws1]) = ck1;
    *reinterpret_cast<uint4*>(&smem[2048 + ws0]) = cv0;
    *reinterpret_cast<uint4*>(&smem[2048 + ws1]) = cv1;
    if (kbeg + 1 < kend) {  // tile kbeg+1 -> regs
        int nb = (kbeg + 1) * 64;
        const ushortt* kp = Kg + (size_t)(nb + row) * 64 + seg * 16;
        ck0 = *reinterpret_cast<const uint4*>(kp);
        ck1 = *reinterpret_cast<const uint4*>(kp + 8);
        const ushortt* vp = Vg + (size_t)row * 4096 + nb + seg * 16;
        cv0 = *reinterpret_cast<const uint4*>(vp);
        cv1 = *reinterpret_cast<const uint4*>(vp + 8);
    }

    for (int kb = kbeg; kb < kend; ++kb) {
        const int cur = (kb - kbeg) & 1;
        const unsigned int rb = cur ? 4096u : 0u;    // read base (tile kb)
        const unsigned int wbs = cur ? 0u : 4096u;   // write base (tile kb+1)
        __syncthreads();
        if (kb + 1 < kend) {                         // regs hold tile kb+1
            *reinterpret_cast<uint4*>(&smem[wbs + ws0]) = ck0;
            *reinterpret_cast<uint4*>(&smem[wbs + ws1]) = ck1;
            *reinterpret_cast<uint4*>(&smem[wbs + 2048 + ws0]) = cv0;
            *reinterpret_cast<uint4*>(&smem[wbs + 2048 + ws1]) = cv1;
        }
        if (kb + 2 < kend) {                         // issue loads for tile kb+2
            int nb = (kb + 2) * 64;
            const ushortt* kp = Kg + (size_t)(nb + row) * 64 + seg * 16;
            ck0 = *reinterpret_cast<const uint4*>(kp);
            ck1 = *reinterpret_cast<const uint4*>(kp + 8);
            const ushortt* vp = Vg + (size_t)row * 4096 + nb + seg * 16;
            cv0 = *reinterpret_cast<const uint4*>(vp);
            cv1 = *reinterpret_cast<const uint4*>(vp + 8);
        }

        floatx16 st = {};
        const unsigned int* kr = &smem[rb + (32 * kh + l31) * 32];
        const int esw = l31 & 7;
        __builtin_amdgcn_s_setprio(1);
        #pragma unroll
        for (int kc = 0; kc < 4; ++kc) {
            union { uint4 v; short8 s8; } af;
            af.v = *reinterpret_cast<const uint4*>(&kr[((2 * kc + h) ^ esw) << 2]);
            st = __builtin_amdgcn_mfma_f32_32x32x16_bf16(af.s8, bq[kc], st, 0, 0, 0);
        }
        __builtin_amdgcn_s_setprio(0);

        // log-depth max tree
        float mx = fmaxf(fmaxf(fmaxf(st[0], st[1]), fmaxf(st[2], st[3])),
                         fmaxf(fmaxf(st[4], st[5]), fmaxf(st[6], st[7])));
        float mx2 = fmaxf(fmaxf(fmaxf(st[8], st[9]), fmaxf(st[10], st[11])),
                          fmaxf(fmaxf(st[12], st[13]), fmaxf(st[14], st[15])));
        mx = fmaxf(mx, mx2);
        mx = fmaxf(mx, __shfl_xor(mx, 32));
        // defer-max: only rescale when the tile max grew by more than 8
        if (!__all(mx <= m_i + 8.f)) {
            float mn = fmaxf(m_i, mx);
            float alpha = fast_exp2(m_i - mn);
            m_i = mn;
            l_i *= alpha;
            #pragma unroll
            for (int r = 0; r < 16; ++r) { ot0[r] *= alpha; ot1[r] *= alpha; }
        }
        float p[16], rs = 0.f;
        #pragma unroll
        for (int r = 0; r < 16; ++r) { p[r] = fast_exp2(st[r] - m_i); rs += p[r]; }
        rs += __shfl_xor(rs, 32);
        l_i += rs;

        unsigned int pk[8], sp[8];
        #pragma unroll
        for (int i = 0; i < 8; ++i) pk[i] = f2bf_pk(p[2 * i], p[2 * i + 1]);
        #pragma unroll
        for (int i = 0; i < 8; ++i) sp[i] = (unsigned int)__shfl_xor((int)pk[i], 32);
        union { unsigned int u[4]; short8 s8; } pb0, pb1;
        pb0.u[0] = h ? sp[2] : pk[0]; pb0.u[1] = h ? sp[3] : pk[1];
        pb0.u[2] = h ? pk[2] : sp[0]; pb0.u[3] = h ? pk[3] : sp[1];
        pb1.u[0] = h ? sp[6] : pk[4]; pb1.u[1] = h ? sp[7] : pk[5];
        pb1.u[2] = h ? pk[6] : sp[4]; pb1.u[3] = h ? pk[7] : sp[5];

        const unsigned int* vr0 = &smem[rb + 2048 + l31 * 32];
        const unsigned int* vr1 = &smem[rb + 2048 + (32 + l31) * 32];
        __builtin_amdgcn_s_setprio(1);
        #pragma unroll
        for (int c = 0; c < 2; ++c) {
            union { uint4 v; short8 s8; } af;
            af.v = *reinterpret_cast<const uint4*>(&vr0[((4 * kh + 2 * c + h) ^ esw) << 2]);
            ot0 = __builtin_amdgcn_mfma_f32_32x32x16_bf16(af.s8, c ? pb1.s8 : pb0.s8, ot0, 0, 0, 0);
            af.v = *reinterpret_cast<const uint4*>(&vr1[((4 * kh + 2 * c + h) ^ esw) << 2]);
            ot1 = __builtin_amdgcn_mfma_f32_32x32x16_bf16(af.s8, c ? pb1.s8 : pb0.s8, ot1, 0, 0, 0);
        }
        __builtin_amdgcn_s_setprio(0);
    }

    // ---- merge kh halves ----
    __syncthreads();
    if (h == 0) {
        smem[8192 + w * 32 + l31] = __float_as_uint(m_i);
        smem[8320 + w * 32 + l31] = __float_as_uint(l_i);
    }
    __syncthreads();
    int pw = 2 * (1 - kh) + qh;
    float m2 = __uint_as_float(smem[8192 + pw * 32 + l31]);
    float l2 = __uint_as_float(smem[8320 + pw * 32 + l31]);
    float mstar = fmaxf(m_i, m2);
    float wself = fast_exp2(m_i - mstar);
    float w2 = fast_exp2(m2 - mstar);
    float lm = wself * l_i + w2 * l2;
    float sc = (gridDim.z == 1) ? (wself / lm) : wself;
    if (gridDim.z > 1 && kh == 0 && h == 0) {
        float2 v; v.x = mstar; v.y = lm;
        ml[((size_t)s * 4 + b) * 4096 + n0 + 32 * qh + l31] = v;
    }
    float* om = reinterpret_cast<float*>(smem);
    if (kh == 0) {
        #pragma unroll
        for (int r = 0; r < 16; ++r) {
            int d0 = (r & 3) + 8 * (r >> 2) + 4 * h;
            om[(32 * qh + l31) * 65 + d0] = sc * ot0[r];
            om[(32 * qh + l31) * 65 + 32 + d0] = sc * ot1[r];
        }
    }
    __syncthreads();
    if (kh == 1) {
        #pragma unroll
        for (int r = 0; r < 16; ++r) {
            int d0 = (r & 3) + 8 * (r >> 2) + 4 * h;
            om[(32 * qh + l31) * 65 + d0] += sc * ot0[r];
            om[(32 * qh + l31) * 65 + 32 + d0] += sc * ot1[r];
        }
    }
    __syncthreads();
    {
        int qq = tid >> 2, dsg = tid & 3;
        unsigned int pkk[8];
        #pragma unroll
        for (int j = 0; j < 8; ++j)
            pkk[j] = f2bf_pk(om[qq * 65 + dsg * 16 + 2 * j], om[qq * 65 + dsg * 16 + 2 * j + 1]);
        ushortt* base = (gridDim.z == 1)
            ? (Ob + ((size_t)b * 4096 + n0) * 64)
            : (Opart + (((size_t)s * 4 + b) * 4096 + n0) * 64);
        uint4* d4 = reinterpret_cast<uint4*>(base + (size_t)qq * 64 + dsg * 16);
        uint4 o0; o0.x = pkk[0]; o0.y = pkk[1]; o0.z = pkk[2]; o0.w = pkk[3];
        uint4 o1; o1.x = pkk[4]; o1.y = pkk[5]; o1.z = pkk[6]; o1.w = pkk[7];
        d4[0] = o0; d4[1] = o1;
    }
}

// ---------------------------------------------------------------------------
// Fused combine + output projection. One block per (32-pixel tile, batch).
// ---------------------------------------------------------------------------
__global__ __launch_bounds__(256, 3) void proj_kernel(
    const ushortt* __restrict__ Opart, const float2* __restrict__ ml,
    const ushortt* __restrict__ Ob, const ushortt* __restrict__ wvb,
    const float* __restrict__ bv, const float* __restrict__ gamma,
    const float* __restrict__ x, float* __restrict__ out, int S) {
    __shared__ ushortt ol[32 * 72];
    const int tid = threadIdx.x;
    const int n0 = blockIdx.x * 32, b = blockIdx.y;

    {   // ---- combine (or plain load when S==1) into LDS ----
        int row = tid >> 3, t8 = tid & 7;       // 32 rows x 8 d-chunks of 8
        int rg = n0 + row;
        if (S == 1) {
            uint4 v = *reinterpret_cast<const uint4*>(
                Ob + ((size_t)b * 4096 + rg) * 64 + t8 * 8);
            *reinterpret_cast<uint4*>(&ol[row * 72 + t8 * 8]) = v;
        } else {
            float2 mls[4];
            float m = -1e30f;
            #pragma unroll 4
            for (int s = 0; s < 4; ++s) {
                mls[s] = ml[((size_t)s * 4 + b) * 4096 + rg];
                m = fmaxf(m, mls[s].x);
            }
            float wgt[4], denom = 0.f;
            #pragma unroll 4
            for (int s = 0; s < 4; ++s) {
                wgt[s] = fast_exp2(mls[s].x - m);
                denom += wgt[s] * mls[s].y;
            }
            float inv = 1.0f / denom;
            float acc[8];
            #pragma unroll
            for (int j = 0; j < 8; ++j) acc[j] = 0.f;
            #pragma unroll 4
            for (int s = 0; s < 4; ++s) {
                union { uint4 v; ushortt hh[8]; } u;
                u.v = *reinterpret_cast<const uint4*>(
                    Opart + (((size_t)s * 4 + b) * 4096 + rg) * 64 + t8 * 8);
                float ww = wgt[s];
                #pragma unroll
                for (int j = 0; j < 8; ++j) acc[j] += ww * bf2f(u.hh[j]);
            }
            uint4 v;
            v.x = f2bf_pk(acc[0] * inv, acc[1] * inv);
            v.y = f2bf_pk(acc[2] * inv, acc[3] * inv);
            v.z = f2bf_pk(acc[4] * inv, acc[5] * inv);
            v.w = f2bf_pk(acc[6] * inv, acc[7] * inv);
            *reinterpret_cast<uint4*>(&ol[row * 72 + t8 * 8]) = v;
        }
    }
    __syncthreads();

    const int w = tid >> 6, lane = tid & 63, q = lane >> 4, l15 = lane & 15;
    short8 bfr[2][2];
    #pragma unroll
    for (int u = 0; u < 2; ++u)
        #pragma unroll
        for (int kc = 0; kc < 2; ++kc)
            bfr[u][kc] = *reinterpret_cast<const short8*>(
                &ol[(16 * u + l15) * 72 + 32 * kc + q * 8]);

    floatx4 acc[8][2];
    #pragma unroll
    for (int t = 0; t < 8; ++t)
        #pragma unroll
        for (int u = 0; u < 2; ++u) acc[t][u] = (floatx4){0.f, 0.f, 0.f, 0.f};

    const int cw = w * 128;
    #pragma unroll
    for (int t = 0; t < 8; ++t) {
        short8 a0 = *reinterpret_cast<const short8*>(
            &wvb[(size_t)(cw + 16 * t + l15) * 64 + q * 8]);
        short8 a1 = *reinterpret_cast<const short8*>(
            &wvb[(size_t)(cw + 16 * t + l15) * 64 + 32 + q * 8]);
        #pragma unroll
        for (int u = 0; u < 2; ++u) {
            acc[t][u] = __builtin_amdgcn_mfma_f32_16x16x32_bf16(a0, bfr[u][0], acc[t][u], 0, 0, 0);
            acc[t][u] = __builtin_amdgcn_mfma_f32_16x16x32_bf16(a1, bfr[u][1], acc[t][u], 0, 0, 0);
        }
    }

    float gm = gamma[0];
    #pragma unroll
    for (int t = 0; t < 8; ++t) {
        #pragma unroll
        for (int r = 0; r < 4; ++r) {
            int c = cw + 16 * t + 4 * q + r;
            float bb = bv[c];
            #pragma unroll
            for (int u = 0; u < 2; ++u) {
                int n = n0 + 16 * u + l15;
                size_t idx = ((size_t)(b * 512 + c)) * 4096 + n;
                out[idx] = gm * (acc[t][u][r] + bb) + x[idx];
            }
        }
    }
}

// ---------------------------------------------------------------------------
extern "C" void kernel_launch(void* const* d_in, const int* in_sizes, int n_in,
                              void* d_out, int out_size, void* d_ws, size_t ws_size,
                              hipStream_t stream) {
    const float* x   = (const float*)d_in[0];
    const float* Wf  = (const float*)d_in[1];
    const float* bf_ = (const float*)d_in[2];
    const float* Wg  = (const float*)d_in[3];
    const float* bg_ = (const float*)d_in[4];
    const float* Wh  = (const float*)d_in[5];
    const float* bh_ = (const float*)d_in[6];
    const float* Wv  = (const float*)d_in[7];
    const float* bv_ = (const float*)d_in[8];
    const float* uf  = (const float*)d_in[9];
    const float* ug  = (const float*)d_in[10];
    const float* uh  = (const float*)d_in[11];
    const float* uv  = (const float*)d_in[12];
    const float* gm  = (const float*)d_in[13];
    float* out = (float*)d_out;

    char* ws = (char*)d_ws;
    float*   sig   = (float*)ws;                         // 256 B
    ushortt* wqkv  = (ushortt*)(ws + 256);               // 196608
    ushortt* wvb   = (ushortt*)(ws + 196864);            // 65536
    ushortt* Qb    = (ushortt*)(ws + 262400);            // 2 MB
    ushortt* Kb    = (ushortt*)(ws + 2359552);           // 2 MB
    ushortt* Vt    = (ushortt*)(ws + 4456704);           // 2 MB  [b][d][n]
    ushortt* Ob    = (ushortt*)(ws + 6553856);           // 2 MB (S==1 only)
    float2*  ml    = (float2*)(ws + 8651008);            // 512 KB (S=4)
    ushortt* Opart = (ushortt*)(ws + 9175296);           // 8 MB bf16 (S=4)

    int S = (ws_size >= (size_t)17563904) ? 4 : 1;

    sigma_kernel<<<4, 256, 0, stream>>>(Wf, uf, Wg, ug, Wh, uh, Wv, uv, sig, wqkv, wvb);
    qkv_kernel<<<dim3(128, 4), 256, 0, stream>>>(x, wqkv, bf_, bg_, bh_, Qb, Kb, Vt);
    attn_kernel<<<dim3(64, 4, S), 256, 0, stream>>>(Qb, Kb, Vt, Opart, ml, Ob, 64 / S);
    proj_kernel<<<dim3(128, 4), 256, 0, stream>>>(Opart, ml, Ob, wvb, bv_, gm, x, out, S);
}